// Round 3
// baseline (712.500 us; speedup 1.0000x reference)
//
#include <hip/hip_runtime.h>
#include <hip/hip_bf16.h>

#define N_PTS 300000
#define GXD 480
#define GYD 360
#define NBATCH 4
#define NVOX (NBATCH * GXD * GYD)
#define OUTC 64
#define BN_EPS 1e-5f
#define CAP 16  // per-voxel list capacity (Poisson lambda=0.43 -> max ~8)

typedef __attribute__((ext_vector_type(8))) __bf16 bf16x8;
typedef __attribute__((ext_vector_type(4))) float f32x4;

__device__ __forceinline__ f32x4 mfma16(bf16x8 a, bf16x8 b, f32x4 c) {
    return __builtin_amdgcn_mfma_f32_16x16x32_bf16(a, b, c, 0, 0, 0);
}

__device__ __forceinline__ float bf2f(unsigned short u) {
    return __uint_as_float(((unsigned)u) << 16);
}
__device__ __forceinline__ unsigned short f2bf(float f) {
    __hip_bfloat16 h = __float2bfloat16(f);
    return *reinterpret_cast<unsigned short*>(&h);
}

// ---------------------------------------------------------------------------
// Fold BN(eval) into linear weights. Weights TRANSPOSED [Nout][Kpad] bf16.
// ---------------------------------------------------------------------------
__global__ __launch_bounds__(256) void fold_kernel(
    const float* __restrict__ bn0g, const float* __restrict__ bn0b,
    const float* __restrict__ bn0m, const float* __restrict__ bn0v,
    const float* __restrict__ bn1g, const float* __restrict__ bn1b,
    const float* __restrict__ bn1m, const float* __restrict__ bn1v,
    const float* __restrict__ bn2g, const float* __restrict__ bn2b,
    const float* __restrict__ bn2m, const float* __restrict__ bn2v,
    const float* __restrict__ bn3g, const float* __restrict__ bn3b,
    const float* __restrict__ bn3m, const float* __restrict__ bn3v,
    const float* __restrict__ w1, const float* __restrict__ bb1,
    const float* __restrict__ w2, const float* __restrict__ bb2,
    const float* __restrict__ w3, const float* __restrict__ bb3,
    const float* __restrict__ w4, const float* __restrict__ bb4,
    __bf16* __restrict__ W1fT, __bf16* __restrict__ W2fT,
    __bf16* __restrict__ W3fT, __bf16* __restrict__ W4T,
    float* __restrict__ Bf)
{
    const int tid = blockIdx.x * blockDim.x + threadIdx.x;
    const int nth = gridDim.x * blockDim.x;

    for (int i = tid; i < 64 * 32; i += nth) {
        int n = i >> 5, k = i & 31;
        float v = 0.f;
        if (k < 9) {
            float s0 = bn0g[k] * rsqrtf(bn0v[k] + BN_EPS);
            float s1 = bn1g[n] * rsqrtf(bn1v[n] + BN_EPS);
            v = s0 * w1[k * 64 + n] * s1;
        }
        W1fT[i] = (__bf16)v;
    }
    for (int n = tid; n < 64; n += nth) {
        float s1 = bn1g[n] * rsqrtf(bn1v[n] + BN_EPS);
        float t1 = bn1b[n] - bn1m[n] * s1;
        float dot = 0.f;
        for (int k = 0; k < 9; k++) {
            float s0 = bn0g[k] * rsqrtf(bn0v[k] + BN_EPS);
            float t0 = bn0b[k] - bn0m[k] * s0;
            dot += t0 * w1[k * 64 + n];
        }
        Bf[n] = (dot + bb1[n]) * s1 + t1;
    }
    for (int i = tid; i < 128 * 64; i += nth) {
        int n = i >> 6, k = i & 63;
        float s2 = bn2g[n] * rsqrtf(bn2v[n] + BN_EPS);
        W2fT[i] = (__bf16)(w2[k * 128 + n] * s2);
    }
    for (int n = tid; n < 128; n += nth) {
        float s2 = bn2g[n] * rsqrtf(bn2v[n] + BN_EPS);
        Bf[64 + n] = bb2[n] * s2 + (bn2b[n] - bn2m[n] * s2);
    }
    for (int i = tid; i < 256 * 128; i += nth) {
        int n = i >> 7, k = i & 127;
        float s3 = bn3g[n] * rsqrtf(bn3v[n] + BN_EPS);
        W3fT[i] = (__bf16)(w3[k * 256 + n] * s3);
    }
    for (int n = tid; n < 256; n += nth) {
        float s3 = bn3g[n] * rsqrtf(bn3v[n] + BN_EPS);
        Bf[192 + n] = bb3[n] * s3 + (bn3b[n] - bn3m[n] * s3);
    }
    for (int i = tid; i < 64 * 256; i += nth) {
        int n = i >> 8, k = i & 255;
        W4T[i] = (__bf16)w4[k * 64 + n];
    }
    for (int n = tid; n < 64; n += nth) Bf[448 + n] = bb4[n];
}

// ---------------------------------------------------------------------------
// Zero per-voxel counters (2.8 MB).
// ---------------------------------------------------------------------------
__global__ __launch_bounds__(256) void zcount_kernel(uint4* __restrict__ c) {
    c[blockIdx.x * 256 + threadIdx.x] = make_uint4(0u, 0u, 0u, 0u);
}

// ---------------------------------------------------------------------------
// Fused MLP (MFMA, bf16) -> coalesced h store + voxel-list build.
// 64 points/block, 16/wave. Only 1 atomic per POINT (vs 64 before).
// ---------------------------------------------------------------------------
__global__ __launch_bounds__(256) void mlp_store(
    const float* __restrict__ x, const int* __restrict__ bidx,
    const int* __restrict__ gx, const int* __restrict__ gy,
    const __bf16* __restrict__ W1, const __bf16* __restrict__ W2,
    const __bf16* __restrict__ W3, const __bf16* __restrict__ W4,
    const float* __restrict__ Bf, unsigned short* __restrict__ h,
    unsigned* __restrict__ count, int* __restrict__ list)
{
    __shared__ __align__(16) __bf16 bufA[4][16][264];
    __shared__ __align__(16) __bf16 bufB[4][16][136];

    const int tid = threadIdx.x;
    const int wid = tid >> 6, lane = tid & 63;
    const int col = lane & 15, kg = lane >> 4;
    const int base = blockIdx.x * 64;

    // voxel list build (1 atomic per point)
    if (lane < 16) {
        int p = base + wid * 16 + lane;
        if (p < N_PTS) {
            int v = (bidx[p] * GXD + gx[p]) * GYD + gy[p];
            unsigned slot = atomicAdd(count + v, 1u);
            if (slot < CAP) list[v * CAP + slot] = p;
        }
    }

    // ---- L1: 9(->32 pad) -> 64
    const int p0 = base + wid * 16 + col;
    bf16x8 a1;
#pragma unroll
    for (int j = 0; j < 8; j++) a1[j] = (__bf16)0.f;
    if (p0 < N_PTS) {
        const float* xp = x + p0 * 9;
#pragma unroll
        for (int j = 0; j < 8; j++) {
            int k = kg * 8 + j;
            if (k < 9) a1[j] = (__bf16)xp[k];
        }
    }
    f32x4 acc1[4];
#pragma unroll
    for (int nt = 0; nt < 4; nt++) {
        float bv = Bf[nt * 16 + col];
        acc1[nt] = (f32x4){bv, bv, bv, bv};
        bf16x8 b = *(const bf16x8*)(W1 + (nt * 16 + col) * 32 + kg * 8);
        acc1[nt] = mfma16(a1, b, acc1[nt]);
    }
#pragma unroll
    for (int nt = 0; nt < 4; nt++)
#pragma unroll
        for (int r = 0; r < 4; r++) {
            float v = acc1[nt][r];
            bufA[wid][kg * 4 + r][nt * 16 + col] = (__bf16)(v > 0.f ? v : 0.f);
        }

    // ---- L2: 64 -> 128
    bf16x8 a2[2];
#pragma unroll
    for (int kt = 0; kt < 2; kt++)
        a2[kt] = *(const bf16x8*)&bufA[wid][col][kt * 32 + kg * 8];
    f32x4 acc2[8];
#pragma unroll
    for (int nt = 0; nt < 8; nt++) {
        float bv = Bf[64 + nt * 16 + col];
        acc2[nt] = (f32x4){bv, bv, bv, bv};
#pragma unroll
        for (int kt = 0; kt < 2; kt++) {
            bf16x8 b = *(const bf16x8*)(W2 + (nt * 16 + col) * 64 + kt * 32 + kg * 8);
            acc2[nt] = mfma16(a2[kt], b, acc2[nt]);
        }
    }
#pragma unroll
    for (int nt = 0; nt < 8; nt++)
#pragma unroll
        for (int r = 0; r < 4; r++) {
            float v = acc2[nt][r];
            bufB[wid][kg * 4 + r][nt * 16 + col] = (__bf16)(v > 0.f ? v : 0.f);
        }

    // ---- L3: 128 -> 256
    bf16x8 a3[4];
#pragma unroll
    for (int kt = 0; kt < 4; kt++)
        a3[kt] = *(const bf16x8*)&bufB[wid][col][kt * 32 + kg * 8];
    f32x4 acc3[16];
#pragma unroll
    for (int nt = 0; nt < 16; nt++) {
        float bv = Bf[192 + nt * 16 + col];
        acc3[nt] = (f32x4){bv, bv, bv, bv};
#pragma unroll
        for (int kt = 0; kt < 4; kt++) {
            bf16x8 b = *(const bf16x8*)(W3 + (nt * 16 + col) * 128 + kt * 32 + kg * 8);
            acc3[nt] = mfma16(a3[kt], b, acc3[nt]);
        }
    }
#pragma unroll
    for (int nt = 0; nt < 16; nt++)
#pragma unroll
        for (int r = 0; r < 4; r++) {
            float v = acc3[nt][r];
            bufA[wid][kg * 4 + r][nt * 16 + col] = (__bf16)(v > 0.f ? v : 0.f);
        }

    // ---- L4: 256 -> 64 (no relu)
    bf16x8 a4[8];
#pragma unroll
    for (int kt = 0; kt < 8; kt++)
        a4[kt] = *(const bf16x8*)&bufA[wid][col][kt * 32 + kg * 8];
    f32x4 acc4[4];
#pragma unroll
    for (int nt = 0; nt < 4; nt++) {
        float bv = Bf[448 + nt * 16 + col];
        acc4[nt] = (f32x4){bv, bv, bv, bv};
#pragma unroll
        for (int kt = 0; kt < 8; kt++) {
            bf16x8 b = *(const bf16x8*)(W4 + (nt * 16 + col) * 256 + kt * 32 + kg * 8);
            acc4[nt] = mfma16(a4[kt], b, acc4[nt]);
        }
    }

    // ---- repack via LDS and store h coalesced (2 KB contiguous per wave)
#pragma unroll
    for (int nt = 0; nt < 4; nt++)
#pragma unroll
        for (int r = 0; r < 4; r++)
            bufB[wid][kg * 4 + r][nt * 16 + col] = (__bf16)acc4[nt][r];

    {
        int pt_l = lane >> 2;          // 16 points
        int c0 = (lane & 3) * 16;      // 16 channels per lane = 32B
        int p = base + wid * 16 + pt_l;
        if (p < N_PTS) {
            const uint4* src = (const uint4*)&bufB[wid][pt_l][c0];
            uint4* dst = (uint4*)(h + (long)p * 64 + c0);
            dst[0] = src[0];
            dst[1] = src[1];
        }
    }
}

// ---------------------------------------------------------------------------
// Gather-max: one wave per voxel. Reads its points' 128B vectors, maxes,
// writes bf16 grid once (empty -> 0). No atomics at all.
// ---------------------------------------------------------------------------
__global__ __launch_bounds__(256) void reduce_kernel(
    const unsigned* __restrict__ count, const int* __restrict__ list,
    const unsigned short* __restrict__ h, unsigned short* __restrict__ grid)
{
    int w = (blockIdx.x * 256 + threadIdx.x) >> 6;  // voxel id
    int lane = threadIdx.x & 63;
    unsigned n = count[w];
    if (n > CAP) n = CAP;
    float m = -3.0e38f;
    for (unsigned i = 0; i < n; i++) {
        int pid = list[w * CAP + i];
        m = fmaxf(m, bf2f(h[(long)pid * 64 + lane]));
    }
    if (n == 0) m = 0.f;
    grid[(long)w * 64 + lane] = f2bf(m);
}

// ---------------------------------------------------------------------------
// 3x3 stride-1 maxpool + transpose [b][x][y][c] -> [b][c][x][y], fp32 out.
// ---------------------------------------------------------------------------
__global__ __launch_bounds__(256) void pool_kernel(
    const unsigned short* __restrict__ grid, float* __restrict__ out)
{
    __shared__ float tile[6][34][65];
    const int tid = threadIdx.x;
    const int x0 = blockIdx.x * 4;
    const int y0 = blockIdx.y * 32;
    const int b = blockIdx.z;

    for (int it = 0; it < 7; it++) {
        int idx = it * 256 + tid;
        if (idx < 6 * 34 * 8) {
            int c8 = idx & 7;
            int yy = (idx >> 3) % 34;
            int xx = (idx >> 3) / 34;
            int gxx = x0 - 1 + xx;
            int gyy = y0 - 1 + yy;
            float f[8];
            if (gxx >= 0 && gxx < GXD && gyy >= 0 && gyy < GYD) {
                uint4 v = *(const uint4*)(grid +
                    ((long)(b * GXD + gxx) * GYD + gyy) * 64 + c8 * 8);
                unsigned uu[4] = {v.x, v.y, v.z, v.w};
#pragma unroll
                for (int j = 0; j < 4; j++) {
                    f[2 * j]     = __uint_as_float(uu[j] << 16);
                    f[2 * j + 1] = __uint_as_float(uu[j] & 0xffff0000u);
                }
            } else {
#pragma unroll
                for (int j = 0; j < 8; j++) f[j] = -3.0e38f;
            }
            float* t = &tile[xx][yy][c8 * 8];
#pragma unroll
            for (int j = 0; j < 8; j++) t[j] = f[j];
        }
    }
    __syncthreads();

    const int y = tid & 31;
    const int cg = tid >> 5;
    const bool yv = (y0 + y) < GYD;
#pragma unroll
    for (int cs = 0; cs < 8; cs++) {
        int c = cg * 8 + cs;
        float rowm[6];
#pragma unroll
        for (int xx = 0; xx < 6; xx++) {
            float e0 = tile[xx][y][c];
            float e1 = tile[xx][y + 1][c];
            float e2 = tile[xx][y + 2][c];
            rowm[xx] = fmaxf(fmaxf(e0, e1), e2);
        }
        if (yv) {
#pragma unroll
            for (int xo = 0; xo < 4; xo++) {
                float m = fmaxf(fmaxf(rowm[xo], rowm[xo + 1]), rowm[xo + 2]);
                out[((long)(b * OUTC + c) * GXD + (x0 + xo)) * GYD + (y0 + y)] = m;
            }
        }
    }
}

extern "C" void kernel_launch(void* const* d_in, const int* in_sizes, int n_in,
                              void* d_out, int out_size, void* d_ws, size_t ws_size,
                              hipStream_t stream)
{
    const float* pt   = (const float*)d_in[0];
    const int* bidx   = (const int*)d_in[1];
    const int* gxp    = (const int*)d_in[2];
    const int* gyp    = (const int*)d_in[3];
    const float* bn0g = (const float*)d_in[4],  *bn0b = (const float*)d_in[5];
    const float* bn0m = (const float*)d_in[6],  *bn0v = (const float*)d_in[7];
    const float* bn1g = (const float*)d_in[8],  *bn1b = (const float*)d_in[9];
    const float* bn1m = (const float*)d_in[10], *bn1v = (const float*)d_in[11];
    const float* bn2g = (const float*)d_in[12], *bn2b = (const float*)d_in[13];
    const float* bn2m = (const float*)d_in[14], *bn2v = (const float*)d_in[15];
    const float* bn3g = (const float*)d_in[16], *bn3b = (const float*)d_in[17];
    const float* bn3m = (const float*)d_in[18], *bn3v = (const float*)d_in[19];
    const float* w1 = (const float*)d_in[20], *bb1 = (const float*)d_in[21];
    const float* w2 = (const float*)d_in[22], *bb2 = (const float*)d_in[23];
    const float* w3 = (const float*)d_in[24], *bb3 = (const float*)d_in[25];
    const float* w4 = (const float*)d_in[26], *bb4 = (const float*)d_in[27];

    char* ws = (char*)d_ws;
    __bf16* W1fT = (__bf16*)ws;              // 2048 elems
    __bf16* W2fT = W1fT + 64 * 32;           // 8192
    __bf16* W3fT = W2fT + 128 * 64;          // 32768
    __bf16* W4T  = W3fT + 256 * 128;         // 16384
    float* Bf = (float*)(ws + 2 * (64 * 32 + 128 * 64 + 256 * 128 + 64 * 256));

    unsigned short* h = (unsigned short*)(ws + 131072);          // 38,400,000 B
    unsigned* count   = (unsigned*)(ws + 38531072);              //  2,764,800 B
    int* list         = (int*)(ws + 41295872);                   // 44,236,800 B
    unsigned short* grid = (unsigned short*)(ws + 85532672);     // 88,473,600 B
    // total 174.0 MB (previous round used 177.0 MB successfully)

    hipLaunchKernelGGL(fold_kernel, dim3(64), dim3(256), 0, stream,
                       bn0g, bn0b, bn0m, bn0v, bn1g, bn1b, bn1m, bn1v,
                       bn2g, bn2b, bn2m, bn2v, bn3g, bn3b, bn3m, bn3v,
                       w1, bb1, w2, bb2, w3, bb3, w4, bb4,
                       W1fT, W2fT, W3fT, W4T, Bf);

    // counts: 691200 u32 = 172800 uint4 = 675 * 256
    hipLaunchKernelGGL(zcount_kernel, dim3(675), dim3(256), 0, stream, (uint4*)count);

    hipLaunchKernelGGL(mlp_store, dim3((N_PTS + 63) / 64), dim3(256), 0, stream,
                       pt, bidx, gxp, gyp, W1fT, W2fT, W3fT, W4T, Bf,
                       h, count, list);

    // one wave per voxel: 691200 voxels / 4 waves per block = 172800 blocks
    hipLaunchKernelGGL(reduce_kernel, dim3(NVOX / 4), dim3(256), 0, stream,
                       count, list, h, grid);

    hipLaunchKernelGGL(pool_kernel, dim3(GXD / 4, (GYD + 31) / 32, NBATCH),
                       dim3(256), 0, stream, grid, (float*)d_out);
}

// Round 5
// 525.500 us; speedup vs baseline: 1.3559x; 1.3559x over previous
//
#include <hip/hip_runtime.h>
#include <hip/hip_bf16.h>

#define N_PTS 300000
#define GXD 480
#define GYD 360
#define NBATCH 4
#define NVOX (NBATCH * GXD * GYD)
#define OUTC 64
#define BN_EPS 1e-5f
#define CAP 16    // per-voxel list capacity (Poisson lambda=0.43 -> max ~8)
#define PPB 1280  // points per block (256 blocks x 1280 = 327680 >= 300000)
#define NITER 10  // PPB / (4 waves * 32 pts)

typedef __attribute__((ext_vector_type(8))) __bf16 bf16x8;
typedef __attribute__((ext_vector_type(4))) float f32x4;

__device__ __forceinline__ f32x4 mfma16(bf16x8 a, bf16x8 b, f32x4 c) {
    return __builtin_amdgcn_mfma_f32_16x16x32_bf16(a, b, c, 0, 0, 0);
}

__device__ __forceinline__ float bf2f(unsigned short u) {
    return __uint_as_float(((unsigned)u) << 16);
}
__device__ __forceinline__ unsigned short f2bf(float f) {
    __hip_bfloat16 h = __float2bfloat16(f);
    return *reinterpret_cast<unsigned short*>(&h);
}

// ---------------------------------------------------------------------------
// Fold BN(eval) into linear weights. Weights TRANSPOSED [Nout][Kin] bf16.
// ---------------------------------------------------------------------------
__global__ __launch_bounds__(256) void fold_kernel(
    const float* __restrict__ bn0g, const float* __restrict__ bn0b,
    const float* __restrict__ bn0m, const float* __restrict__ bn0v,
    const float* __restrict__ bn1g, const float* __restrict__ bn1b,
    const float* __restrict__ bn1m, const float* __restrict__ bn1v,
    const float* __restrict__ bn2g, const float* __restrict__ bn2b,
    const float* __restrict__ bn2m, const float* __restrict__ bn2v,
    const float* __restrict__ bn3g, const float* __restrict__ bn3b,
    const float* __restrict__ bn3m, const float* __restrict__ bn3v,
    const float* __restrict__ w1, const float* __restrict__ bb1,
    const float* __restrict__ w2, const float* __restrict__ bb2,
    const float* __restrict__ w3, const float* __restrict__ bb3,
    const float* __restrict__ w4, const float* __restrict__ bb4,
    __bf16* __restrict__ W1fT, __bf16* __restrict__ W2fT,
    __bf16* __restrict__ W3fT, __bf16* __restrict__ W4T,
    float* __restrict__ Bf)
{
    const int tid = blockIdx.x * blockDim.x + threadIdx.x;
    const int nth = gridDim.x * blockDim.x;

    for (int i = tid; i < 64 * 32; i += nth) {
        int n = i >> 5, k = i & 31;
        float v = 0.f;
        if (k < 9) {
            float s0 = bn0g[k] * rsqrtf(bn0v[k] + BN_EPS);
            float s1 = bn1g[n] * rsqrtf(bn1v[n] + BN_EPS);
            v = s0 * w1[k * 64 + n] * s1;
        }
        W1fT[i] = (__bf16)v;
    }
    for (int n = tid; n < 64; n += nth) {
        float s1 = bn1g[n] * rsqrtf(bn1v[n] + BN_EPS);
        float t1 = bn1b[n] - bn1m[n] * s1;
        float dot = 0.f;
        for (int k = 0; k < 9; k++) {
            float s0 = bn0g[k] * rsqrtf(bn0v[k] + BN_EPS);
            float t0 = bn0b[k] - bn0m[k] * s0;
            dot += t0 * w1[k * 64 + n];
        }
        Bf[n] = (dot + bb1[n]) * s1 + t1;
    }
    for (int i = tid; i < 128 * 64; i += nth) {
        int n = i >> 6, k = i & 63;
        float s2 = bn2g[n] * rsqrtf(bn2v[n] + BN_EPS);
        W2fT[i] = (__bf16)(w2[k * 128 + n] * s2);
    }
    for (int n = tid; n < 128; n += nth) {
        float s2 = bn2g[n] * rsqrtf(bn2v[n] + BN_EPS);
        Bf[64 + n] = bb2[n] * s2 + (bn2b[n] - bn2m[n] * s2);
    }
    for (int i = tid; i < 256 * 128; i += nth) {
        int n = i >> 7, k = i & 127;
        float s3 = bn3g[n] * rsqrtf(bn3v[n] + BN_EPS);
        W3fT[i] = (__bf16)(w3[k * 256 + n] * s3);
    }
    for (int n = tid; n < 256; n += nth) {
        float s3 = bn3g[n] * rsqrtf(bn3v[n] + BN_EPS);
        Bf[192 + n] = bb3[n] * s3 + (bn3b[n] - bn3m[n] * s3);
    }
    for (int i = tid; i < 64 * 256; i += nth) {
        int n = i >> 8, k = i & 255;
        W4T[i] = (__bf16)w4[k * 64 + n];
    }
    for (int n = tid; n < 64; n += nth) Bf[448 + n] = bb4[n];
}

__global__ __launch_bounds__(256) void zcount_kernel(uint4* __restrict__ c) {
    c[blockIdx.x * 256 + threadIdx.x] = make_uint4(0u, 0u, 0u, 0u);
}

// ---------------------------------------------------------------------------
// Fused MLP: weights staged ONCE per block into LDS (bank-spread padded
// strides), 256 persistent blocks x 10 iters x 128 pts. Each wave: dual
// 16-pt tiles sharing every B-fragment. 1 atomic per point for voxel lists.
// LDS: 126,976 (weights) + 33,792 (act buf) = 160,768 B <= 163,840.
// ---------------------------------------------------------------------------
__global__ __launch_bounds__(256, 1) void mlp_store(
    const float* __restrict__ x, const int* __restrict__ bidx,
    const int* __restrict__ gx, const int* __restrict__ gy,
    const __bf16* __restrict__ W1, const __bf16* __restrict__ W2,
    const __bf16* __restrict__ W3, const __bf16* __restrict__ W4,
    const float* __restrict__ Bf, unsigned short* __restrict__ h,
    unsigned* __restrict__ count, int* __restrict__ list)
{
    __shared__ __bf16 w1s[64 * 40];     // row stride 40 elems
    __shared__ __bf16 w2s[128 * 72];    // 144B = 36w ≡ 4 mod 32 -> uniform banks
    __shared__ __bf16 w3s[256 * 136];   // 272B = 68w ≡ 4 mod 32
    __shared__ __bf16 w4s[64 * 264];    // 528B = 132w ≡ 4 mod 32
    __shared__ __align__(16) __bf16 bufA[4][16][264];

    const int tid = threadIdx.x;
    const int wid = tid >> 6, lane = tid & 63;
    const int col = lane & 15, kg = lane >> 4;

    // ---- stage weights global -> LDS (once per block)
    {
        const uint4* g1 = (const uint4*)W1;
        for (int i = tid; i < 64 * 4; i += 256) {
            int r = i >> 2, q = i & 3;
            *(uint4*)&w1s[r * 40 + q * 8] = g1[r * 4 + q];
        }
        const uint4* g2 = (const uint4*)W2;
        for (int i = tid; i < 128 * 8; i += 256) {
            int r = i >> 3, q = i & 7;
            *(uint4*)&w2s[r * 72 + q * 8] = g2[r * 8 + q];
        }
        const uint4* g3 = (const uint4*)W3;
        for (int i = tid; i < 256 * 16; i += 256) {
            int r = i >> 4, q = i & 15;
            *(uint4*)&w3s[r * 136 + q * 8] = g3[r * 16 + q];
        }
        const uint4* g4 = (const uint4*)W4;
        for (int i = tid; i < 64 * 32; i += 256) {
            int r = i >> 5, q = i & 31;
            *(uint4*)&w4s[r * 264 + q * 8] = g4[r * 32 + q];
        }
    }

    // ---- bias preload to registers (per-lane, depends only on col)
    float bias1[4], bias2[8], bias3[16], bias4[4];
#pragma unroll
    for (int i = 0; i < 4; i++) bias1[i] = Bf[i * 16 + col];
#pragma unroll
    for (int i = 0; i < 8; i++) bias2[i] = Bf[64 + i * 16 + col];
#pragma unroll
    for (int i = 0; i < 16; i++) bias3[i] = Bf[192 + i * 16 + col];
#pragma unroll
    for (int i = 0; i < 4; i++) bias4[i] = Bf[448 + i * 16 + col];

    __syncthreads();

    const int blkBase = blockIdx.x * PPB;

#pragma unroll 1
    for (int it = 0; it < NITER; it++) {
        const int tb = blkBase + it * 128 + wid * 32;
        if (tb >= N_PTS) break;

        // voxel list build: 1 atomic per point (lanes 0..31 = this wave's 32 pts)
        if (lane < 32) {
            int p = tb + lane;
            if (p < N_PTS) {
                int v = (bidx[p] * GXD + gx[p]) * GYD + gy[p];
                unsigned slot = atomicAdd(count + v, 1u);
                if (slot < CAP) list[v * CAP + slot] = p;
            }
        }

        // ---- L1: 9(->32) -> 64
        bf16x8 a1[2];
#pragma unroll
        for (int t = 0; t < 2; t++) {
#pragma unroll
            for (int j = 0; j < 8; j++) a1[t][j] = (__bf16)0.f;
            int p0 = tb + t * 16 + col;
            if (p0 < N_PTS) {
                const float* xp = x + (long)p0 * 9;
#pragma unroll
                for (int j = 0; j < 8; j++) {
                    int k = kg * 8 + j;
                    if (k < 9) a1[t][j] = (__bf16)xp[k];
                }
            }
        }
        f32x4 acc1[2][4];
#pragma unroll
        for (int nt = 0; nt < 4; nt++) {
            bf16x8 b = *(const bf16x8*)&w1s[(nt * 16 + col) * 40 + kg * 8];
            float bv = bias1[nt];
#pragma unroll
            for (int t = 0; t < 2; t++)
                acc1[t][nt] = mfma16(a1[t], b, (f32x4){bv, bv, bv, bv});
        }
        bf16x8 a2[2][2];
#pragma unroll
        for (int t = 0; t < 2; t++) {
#pragma unroll
            for (int nt = 0; nt < 4; nt++)
#pragma unroll
                for (int r = 0; r < 4; r++) {
                    float v = acc1[t][nt][r];
                    bufA[wid][kg * 4 + r][nt * 16 + col] = (__bf16)(v > 0.f ? v : 0.f);
                }
#pragma unroll
            for (int kt = 0; kt < 2; kt++)
                a2[t][kt] = *(const bf16x8*)&bufA[wid][col][kt * 32 + kg * 8];
        }

        // ---- L2: 64 -> 128
        f32x4 acc2[2][8];
#pragma unroll
        for (int nt = 0; nt < 8; nt++) {
            float bv = bias2[nt];
#pragma unroll
            for (int t = 0; t < 2; t++) acc2[t][nt] = (f32x4){bv, bv, bv, bv};
#pragma unroll
            for (int kt = 0; kt < 2; kt++) {
                bf16x8 b = *(const bf16x8*)&w2s[(nt * 16 + col) * 72 + kt * 32 + kg * 8];
#pragma unroll
                for (int t = 0; t < 2; t++)
                    acc2[t][nt] = mfma16(a2[t][kt], b, acc2[t][nt]);
            }
        }
        bf16x8 a3[2][4];
#pragma unroll
        for (int t = 0; t < 2; t++) {
#pragma unroll
            for (int nt = 0; nt < 8; nt++)
#pragma unroll
                for (int r = 0; r < 4; r++) {
                    float v = acc2[t][nt][r];
                    bufA[wid][kg * 4 + r][nt * 16 + col] = (__bf16)(v > 0.f ? v : 0.f);
                }
#pragma unroll
            for (int kt = 0; kt < 4; kt++)
                a3[t][kt] = *(const bf16x8*)&bufA[wid][col][kt * 32 + kg * 8];
        }

        // ---- L3: 128 -> 256
        f32x4 acc3[2][16];
#pragma unroll
        for (int nt = 0; nt < 16; nt++) {
            float bv = bias3[nt];
#pragma unroll
            for (int t = 0; t < 2; t++) acc3[t][nt] = (f32x4){bv, bv, bv, bv};
#pragma unroll
            for (int kt = 0; kt < 4; kt++) {
                bf16x8 b = *(const bf16x8*)&w3s[(nt * 16 + col) * 136 + kt * 32 + kg * 8];
#pragma unroll
                for (int t = 0; t < 2; t++)
                    acc3[t][nt] = mfma16(a3[t][kt], b, acc3[t][nt]);
            }
        }
        bf16x8 a4[2][8];
#pragma unroll
        for (int t = 0; t < 2; t++) {
#pragma unroll
            for (int nt = 0; nt < 16; nt++)
#pragma unroll
                for (int r = 0; r < 4; r++) {
                    float v = acc3[t][nt][r];
                    bufA[wid][kg * 4 + r][nt * 16 + col] = (__bf16)(v > 0.f ? v : 0.f);
                }
#pragma unroll
            for (int kt = 0; kt < 8; kt++)
                a4[t][kt] = *(const bf16x8*)&bufA[wid][col][kt * 32 + kg * 8];
        }

        // ---- L4: 256 -> 64 (no relu), then coalesced h store via LDS repack
        f32x4 acc4[2][4];
#pragma unroll
        for (int nt = 0; nt < 4; nt++) {
            float bv = bias4[nt];
#pragma unroll
            for (int t = 0; t < 2; t++) acc4[t][nt] = (f32x4){bv, bv, bv, bv};
#pragma unroll
            for (int kt = 0; kt < 8; kt++) {
                bf16x8 b = *(const bf16x8*)&w4s[(nt * 16 + col) * 264 + kt * 32 + kg * 8];
#pragma unroll
                for (int t = 0; t < 2; t++)
                    acc4[t][nt] = mfma16(a4[t][kt], b, acc4[t][nt]);
            }
        }
#pragma unroll
        for (int t = 0; t < 2; t++) {
#pragma unroll
            for (int nt = 0; nt < 4; nt++)
#pragma unroll
                for (int r = 0; r < 4; r++)
                    bufA[wid][kg * 4 + r][nt * 16 + col] = (__bf16)acc4[t][nt][r];
            int pt_l = lane >> 2;
            int c0 = (lane & 3) * 16;
            int p = tb + t * 16 + pt_l;
            if (p < N_PTS) {
                const uint4* src = (const uint4*)&bufA[wid][pt_l][c0];
                uint4* dst = (uint4*)(h + (long)p * 64 + c0);
                dst[0] = src[0];
                dst[1] = src[1];
            }
        }
    }
}

// ---------------------------------------------------------------------------
// Gather-max: each wave handles 16 voxels (10,800 blocks, was 172,800 —
// dispatch grind eliminated). Coalesced 128B row reads/writes.
// ---------------------------------------------------------------------------
__global__ __launch_bounds__(256) void reduce_kernel(
    const unsigned* __restrict__ count, const int* __restrict__ list,
    const unsigned short* __restrict__ h, unsigned short* __restrict__ grid)
{
    const int wid = threadIdx.x >> 6, lane = threadIdx.x & 63;
    const int vbase = blockIdx.x * 64 + wid * 16;
#pragma unroll 1
    for (int i = 0; i < 16; i++) {
        int v = vbase + i;
        unsigned n = count[v];
        if (n > CAP) n = CAP;
        float m = -3.0e38f;
        for (unsigned j = 0; j < n; j++) {
            int pid = list[v * CAP + j];
            m = fmaxf(m, bf2f(h[(long)pid * 64 + lane]));
        }
        if (n == 0) m = 0.f;
        grid[(long)v * 64 + lane] = f2bf(m);
    }
}

// ---------------------------------------------------------------------------
// 3x3 stride-1 maxpool + transpose [b][x][y][c] -> [b][c][x][y], fp32 out.
// ---------------------------------------------------------------------------
__global__ __launch_bounds__(256) void pool_kernel(
    const unsigned short* __restrict__ grid, float* __restrict__ out)
{
    __shared__ float tile[6][34][65];
    const int tid = threadIdx.x;
    const int x0 = blockIdx.x * 4;
    const int y0 = blockIdx.y * 32;
    const int b = blockIdx.z;

    for (int it = 0; it < 7; it++) {
        int idx = it * 256 + tid;
        if (idx < 6 * 34 * 8) {
            int c8 = idx & 7;
            int yy = (idx >> 3) % 34;
            int xx = (idx >> 3) / 34;
            int gxx = x0 - 1 + xx;
            int gyy = y0 - 1 + yy;
            float f[8];
            if (gxx >= 0 && gxx < GXD && gyy >= 0 && gyy < GYD) {
                uint4 v = *(const uint4*)(grid +
                    ((long)(b * GXD + gxx) * GYD + gyy) * 64 + c8 * 8);
                unsigned uu[4] = {v.x, v.y, v.z, v.w};
#pragma unroll
                for (int j = 0; j < 4; j++) {
                    f[2 * j]     = __uint_as_float(uu[j] << 16);
                    f[2 * j + 1] = __uint_as_float(uu[j] & 0xffff0000u);
                }
            } else {
#pragma unroll
                for (int j = 0; j < 8; j++) f[j] = -3.0e38f;
            }
            float* t = &tile[xx][yy][c8 * 8];
#pragma unroll
            for (int j = 0; j < 8; j++) t[j] = f[j];
        }
    }
    __syncthreads();

    const int y = tid & 31;
    const int cg = tid >> 5;
    const bool yv = (y0 + y) < GYD;
#pragma unroll
    for (int cs = 0; cs < 8; cs++) {
        int c = cg * 8 + cs;
        float rowm[6];
#pragma unroll
        for (int xx = 0; xx < 6; xx++) {
            float e0 = tile[xx][y][c];
            float e1 = tile[xx][y + 1][c];
            float e2 = tile[xx][y + 2][c];
            rowm[xx] = fmaxf(fmaxf(e0, e1), e2);
        }
        if (yv) {
#pragma unroll
            for (int xo = 0; xo < 4; xo++) {
                float m = fmaxf(fmaxf(rowm[xo], rowm[xo + 1]), rowm[xo + 2]);
                out[((long)(b * OUTC + c) * GXD + (x0 + xo)) * GYD + (y0 + y)] = m;
            }
        }
    }
}

extern "C" void kernel_launch(void* const* d_in, const int* in_sizes, int n_in,
                              void* d_out, int out_size, void* d_ws, size_t ws_size,
                              hipStream_t stream)
{
    const float* pt   = (const float*)d_in[0];
    const int* bidx   = (const int*)d_in[1];
    const int* gxp    = (const int*)d_in[2];
    const int* gyp    = (const int*)d_in[3];
    const float* bn0g = (const float*)d_in[4],  *bn0b = (const float*)d_in[5];
    const float* bn0m = (const float*)d_in[6],  *bn0v = (const float*)d_in[7];
    const float* bn1g = (const float*)d_in[8],  *bn1b = (const float*)d_in[9];
    const float* bn1m = (const float*)d_in[10], *bn1v = (const float*)d_in[11];
    const float* bn2g = (const float*)d_in[12], *bn2b = (const float*)d_in[13];
    const float* bn2m = (const float*)d_in[14], *bn2v = (const float*)d_in[15];
    const float* bn3g = (const float*)d_in[16], *bn3b = (const float*)d_in[17];
    const float* bn3m = (const float*)d_in[18], *bn3v = (const float*)d_in[19];
    const float* w1 = (const float*)d_in[20], *bb1 = (const float*)d_in[21];
    const float* w2 = (const float*)d_in[22], *bb2 = (const float*)d_in[23];
    const float* w3 = (const float*)d_in[24], *bb3 = (const float*)d_in[25];
    const float* w4 = (const float*)d_in[26], *bb4 = (const float*)d_in[27];

    char* ws = (char*)d_ws;
    __bf16* W1fT = (__bf16*)ws;              // 2048 elems
    __bf16* W2fT = W1fT + 64 * 32;           // 8192
    __bf16* W3fT = W2fT + 128 * 64;          // 32768
    __bf16* W4T  = W3fT + 256 * 128;         // 16384
    float* Bf = (float*)(ws + 2 * (64 * 32 + 128 * 64 + 256 * 128 + 64 * 256));

    unsigned short* h = (unsigned short*)(ws + 131072);          // 38,400,000 B
    unsigned* count   = (unsigned*)(ws + 38531072);              //  2,764,800 B
    int* list         = (int*)(ws + 41295872);                   // 44,236,800 B
    unsigned short* grid = (unsigned short*)(ws + 85532672);     // 88,473,600 B

    hipLaunchKernelGGL(fold_kernel, dim3(64), dim3(256), 0, stream,
                       bn0g, bn0b, bn0m, bn0v, bn1g, bn1b, bn1m, bn1v,
                       bn2g, bn2b, bn2m, bn2v, bn3g, bn3b, bn3m, bn3v,
                       w1, bb1, w2, bb2, w3, bb3, w4, bb4,
                       W1fT, W2fT, W3fT, W4T, Bf);

    hipLaunchKernelGGL(zcount_kernel, dim3(675), dim3(256), 0, stream, (uint4*)count);

    hipLaunchKernelGGL(mlp_store, dim3(256), dim3(256), 0, stream,
                       pt, bidx, gxp, gyp, W1fT, W2fT, W3fT, W4T, Bf,
                       h, count, list);

    hipLaunchKernelGGL(reduce_kernel, dim3(NVOX / 64), dim3(256), 0, stream,
                       count, list, h, grid);

    hipLaunchKernelGGL(pool_kernel, dim3(GXD / 4, (GYD + 31) / 32, NBATCH),
                       dim3(256), 0, stream, grid, (float*)d_out);
}

// Round 6
// 506.101 us; speedup vs baseline: 1.4078x; 1.0383x over previous
//
#include <hip/hip_runtime.h>
#include <hip/hip_bf16.h>

#define N_PTS 300000
#define GXD 480
#define GYD 360
#define NBATCH 4
#define NVOX (NBATCH * GXD * GYD)
#define OUTC 64
#define BN_EPS 1e-5f
#define CAP 16    // per-voxel list capacity (Poisson lambda=0.43 -> max ~8)
#define PPB 1280  // points per block (256 blocks x 1280 = 327680 >= 300000)
#define NITER 5   // PPB / (8 waves * 32 pts)

typedef __attribute__((ext_vector_type(8))) __bf16 bf16x8;
typedef __attribute__((ext_vector_type(4))) float f32x4;

__device__ __forceinline__ f32x4 mfma16(bf16x8 a, bf16x8 b, f32x4 c) {
    return __builtin_amdgcn_mfma_f32_16x16x32_bf16(a, b, c, 0, 0, 0);
}

__device__ __forceinline__ float bf2f(unsigned short u) {
    return __uint_as_float(((unsigned)u) << 16);
}
__device__ __forceinline__ unsigned short f2bf(float f) {
    __hip_bfloat16 h = __float2bfloat16(f);
    return *reinterpret_cast<unsigned short*>(&h);
}

// ---------------------------------------------------------------------------
// Fold BN(eval) into linear weights. Weights TRANSPOSED [Nout][Kin] bf16.
// ---------------------------------------------------------------------------
__global__ __launch_bounds__(256) void fold_kernel(
    const float* __restrict__ bn0g, const float* __restrict__ bn0b,
    const float* __restrict__ bn0m, const float* __restrict__ bn0v,
    const float* __restrict__ bn1g, const float* __restrict__ bn1b,
    const float* __restrict__ bn1m, const float* __restrict__ bn1v,
    const float* __restrict__ bn2g, const float* __restrict__ bn2b,
    const float* __restrict__ bn2m, const float* __restrict__ bn2v,
    const float* __restrict__ bn3g, const float* __restrict__ bn3b,
    const float* __restrict__ bn3m, const float* __restrict__ bn3v,
    const float* __restrict__ w1, const float* __restrict__ bb1,
    const float* __restrict__ w2, const float* __restrict__ bb2,
    const float* __restrict__ w3, const float* __restrict__ bb3,
    const float* __restrict__ w4, const float* __restrict__ bb4,
    __bf16* __restrict__ W1fT, __bf16* __restrict__ W2fT,
    __bf16* __restrict__ W3fT, __bf16* __restrict__ W4T,
    float* __restrict__ Bf)
{
    const int tid = blockIdx.x * blockDim.x + threadIdx.x;
    const int nth = gridDim.x * blockDim.x;

    for (int i = tid; i < 64 * 32; i += nth) {
        int n = i >> 5, k = i & 31;
        float v = 0.f;
        if (k < 9) {
            float s0 = bn0g[k] * rsqrtf(bn0v[k] + BN_EPS);
            float s1 = bn1g[n] * rsqrtf(bn1v[n] + BN_EPS);
            v = s0 * w1[k * 64 + n] * s1;
        }
        W1fT[i] = (__bf16)v;
    }
    for (int n = tid; n < 64; n += nth) {
        float s1 = bn1g[n] * rsqrtf(bn1v[n] + BN_EPS);
        float t1 = bn1b[n] - bn1m[n] * s1;
        float dot = 0.f;
        for (int k = 0; k < 9; k++) {
            float s0 = bn0g[k] * rsqrtf(bn0v[k] + BN_EPS);
            float t0 = bn0b[k] - bn0m[k] * s0;
            dot += t0 * w1[k * 64 + n];
        }
        Bf[n] = (dot + bb1[n]) * s1 + t1;
    }
    for (int i = tid; i < 128 * 64; i += nth) {
        int n = i >> 6, k = i & 63;
        float s2 = bn2g[n] * rsqrtf(bn2v[n] + BN_EPS);
        W2fT[i] = (__bf16)(w2[k * 128 + n] * s2);
    }
    for (int n = tid; n < 128; n += nth) {
        float s2 = bn2g[n] * rsqrtf(bn2v[n] + BN_EPS);
        Bf[64 + n] = bb2[n] * s2 + (bn2b[n] - bn2m[n] * s2);
    }
    for (int i = tid; i < 256 * 128; i += nth) {
        int n = i >> 7, k = i & 127;
        float s3 = bn3g[n] * rsqrtf(bn3v[n] + BN_EPS);
        W3fT[i] = (__bf16)(w3[k * 256 + n] * s3);
    }
    for (int n = tid; n < 256; n += nth) {
        float s3 = bn3g[n] * rsqrtf(bn3v[n] + BN_EPS);
        Bf[192 + n] = bb3[n] * s3 + (bn3b[n] - bn3m[n] * s3);
    }
    for (int i = tid; i < 64 * 256; i += nth) {
        int n = i >> 8, k = i & 255;
        W4T[i] = (__bf16)w4[k * 64 + n];
    }
    for (int n = tid; n < 64; n += nth) Bf[448 + n] = bb4[n];
}

__global__ __launch_bounds__(256) void zcount_kernel(uint4* __restrict__ c) {
    c[blockIdx.x * 256 + threadIdx.x] = make_uint4(0u, 0u, 0u, 0u);
}

// ---------------------------------------------------------------------------
// Fused MLP: weights in LDS once per block; 512 threads = 8 waves = 2/SIMD
// (was 1/SIMD -> 76% idle). Per-wave act buffer 16x136 (256-wide transpose
// done in two 128-ch halves; intra-wave in-order DS). Dual 16-pt tiles.
// LDS: 126,976 (weights) + 34,816 (act) = 161,792 <= 163,840.
// ---------------------------------------------------------------------------
__global__ __launch_bounds__(512, 2) void mlp_store(
    const float* __restrict__ x, const int* __restrict__ bidx,
    const int* __restrict__ gx, const int* __restrict__ gy,
    const __bf16* __restrict__ W1, const __bf16* __restrict__ W2,
    const __bf16* __restrict__ W3, const __bf16* __restrict__ W4,
    const float* __restrict__ Bf, unsigned short* __restrict__ h,
    unsigned* __restrict__ count, int* __restrict__ list)
{
    __shared__ __bf16 w1s[64 * 40];
    __shared__ __bf16 w2s[128 * 72];    // 36w ≡ 4 mod 32 -> spread banks
    __shared__ __bf16 w3s[256 * 136];   // 68w ≡ 4 mod 32
    __shared__ __bf16 w4s[64 * 264];    // 132w ≡ 4 mod 32
    __shared__ __align__(16) __bf16 bufA[8][16][136];

    const int tid = threadIdx.x;
    const int wid = tid >> 6, lane = tid & 63;
    const int col = lane & 15, kg = lane >> 4;

    // ---- stage weights global -> LDS (once per block)
    {
        const uint4* g1 = (const uint4*)W1;
        for (int i = tid; i < 64 * 4; i += 512) {
            int r = i >> 2, q = i & 3;
            *(uint4*)&w1s[r * 40 + q * 8] = g1[r * 4 + q];
        }
        const uint4* g2 = (const uint4*)W2;
        for (int i = tid; i < 128 * 8; i += 512) {
            int r = i >> 3, q = i & 7;
            *(uint4*)&w2s[r * 72 + q * 8] = g2[r * 8 + q];
        }
        const uint4* g3 = (const uint4*)W3;
        for (int i = tid; i < 256 * 16; i += 512) {
            int r = i >> 4, q = i & 15;
            *(uint4*)&w3s[r * 136 + q * 8] = g3[r * 16 + q];
        }
        const uint4* g4 = (const uint4*)W4;
        for (int i = tid; i < 64 * 32; i += 512) {
            int r = i >> 5, q = i & 31;
            *(uint4*)&w4s[r * 264 + q * 8] = g4[r * 32 + q];
        }
    }

    // ---- bias preload to registers
    float bias1[4], bias2[8], bias3[16], bias4[4];
#pragma unroll
    for (int i = 0; i < 4; i++) bias1[i] = Bf[i * 16 + col];
#pragma unroll
    for (int i = 0; i < 8; i++) bias2[i] = Bf[64 + i * 16 + col];
#pragma unroll
    for (int i = 0; i < 16; i++) bias3[i] = Bf[192 + i * 16 + col];
#pragma unroll
    for (int i = 0; i < 4; i++) bias4[i] = Bf[448 + i * 16 + col];

    __syncthreads();

    const int blkBase = blockIdx.x * PPB;

#pragma unroll 1
    for (int it = 0; it < NITER; it++) {
        const int tb = blkBase + it * 256 + wid * 32;
        if (tb >= N_PTS) break;

        // voxel list build: 1 atomic per point
        if (lane < 32) {
            int p = tb + lane;
            if (p < N_PTS) {
                int v = (bidx[p] * GXD + gx[p]) * GYD + gy[p];
                unsigned slot = atomicAdd(count + v, 1u);
                if (slot < CAP) list[v * CAP + slot] = p;
            }
        }

        // ---- L1: 9(->32) -> 64
        bf16x8 a1[2];
#pragma unroll
        for (int t = 0; t < 2; t++) {
#pragma unroll
            for (int j = 0; j < 8; j++) a1[t][j] = (__bf16)0.f;
            int p0 = tb + t * 16 + col;
            if (p0 < N_PTS) {
                const float* xp = x + (long)p0 * 9;
#pragma unroll
                for (int j = 0; j < 8; j++) {
                    int k = kg * 8 + j;
                    if (k < 9) a1[t][j] = (__bf16)xp[k];
                }
            }
        }
        f32x4 acc1[2][4];
#pragma unroll
        for (int nt = 0; nt < 4; nt++) {
            bf16x8 b = *(const bf16x8*)&w1s[(nt * 16 + col) * 40 + kg * 8];
            float bv = bias1[nt];
#pragma unroll
            for (int t = 0; t < 2; t++)
                acc1[t][nt] = mfma16(a1[t], b, (f32x4){bv, bv, bv, bv});
        }
        bf16x8 a2[2][2];
#pragma unroll
        for (int t = 0; t < 2; t++) {
#pragma unroll
            for (int nt = 0; nt < 4; nt++)
#pragma unroll
                for (int r = 0; r < 4; r++) {
                    float v = acc1[t][nt][r];
                    bufA[wid][kg * 4 + r][nt * 16 + col] = (__bf16)(v > 0.f ? v : 0.f);
                }
#pragma unroll
            for (int kt = 0; kt < 2; kt++)
                a2[t][kt] = *(const bf16x8*)&bufA[wid][col][kt * 32 + kg * 8];
        }

        // ---- L2: 64 -> 128
        f32x4 acc2[2][8];
#pragma unroll
        for (int nt = 0; nt < 8; nt++) {
            float bv = bias2[nt];
#pragma unroll
            for (int t = 0; t < 2; t++) acc2[t][nt] = (f32x4){bv, bv, bv, bv};
#pragma unroll
            for (int kt = 0; kt < 2; kt++) {
                bf16x8 b = *(const bf16x8*)&w2s[(nt * 16 + col) * 72 + kt * 32 + kg * 8];
#pragma unroll
                for (int t = 0; t < 2; t++)
                    acc2[t][nt] = mfma16(a2[t][kt], b, acc2[t][nt]);
            }
        }
        bf16x8 a3[2][4];
#pragma unroll
        for (int t = 0; t < 2; t++) {
#pragma unroll
            for (int nt = 0; nt < 8; nt++)
#pragma unroll
                for (int r = 0; r < 4; r++) {
                    float v = acc2[t][nt][r];
                    bufA[wid][kg * 4 + r][nt * 16 + col] = (__bf16)(v > 0.f ? v : 0.f);
                }
#pragma unroll
            for (int kt = 0; kt < 4; kt++)
                a3[t][kt] = *(const bf16x8*)&bufA[wid][col][kt * 32 + kg * 8];
        }

        // ---- L3: 128 -> 256
        f32x4 acc3[2][16];
#pragma unroll
        for (int nt = 0; nt < 16; nt++) {
            float bv = bias3[nt];
#pragma unroll
            for (int t = 0; t < 2; t++) acc3[t][nt] = (f32x4){bv, bv, bv, bv};
#pragma unroll
            for (int kt = 0; kt < 4; kt++) {
                bf16x8 b = *(const bf16x8*)&w3s[(nt * 16 + col) * 136 + kt * 32 + kg * 8];
#pragma unroll
                for (int t = 0; t < 2; t++)
                    acc3[t][nt] = mfma16(a3[t][kt], b, acc3[t][nt]);
            }
        }
        // ---- transpose 256-wide output in TWO 128-ch halves via 136-wide buf
        bf16x8 a4[2][8];
#pragma unroll
        for (int t = 0; t < 2; t++) {
#pragma unroll
            for (int nt = 0; nt < 8; nt++)
#pragma unroll
                for (int r = 0; r < 4; r++) {
                    float v = acc3[t][nt][r];
                    bufA[wid][kg * 4 + r][nt * 16 + col] = (__bf16)(v > 0.f ? v : 0.f);
                }
#pragma unroll
            for (int kt = 0; kt < 4; kt++)
                a4[t][kt] = *(const bf16x8*)&bufA[wid][col][kt * 32 + kg * 8];
#pragma unroll
            for (int nt = 8; nt < 16; nt++)
#pragma unroll
                for (int r = 0; r < 4; r++) {
                    float v = acc3[t][nt][r];
                    bufA[wid][kg * 4 + r][(nt - 8) * 16 + col] = (__bf16)(v > 0.f ? v : 0.f);
                }
#pragma unroll
            for (int kt = 4; kt < 8; kt++)
                a4[t][kt] = *(const bf16x8*)&bufA[wid][col][(kt - 4) * 32 + kg * 8];
        }

        // ---- L4: 256 -> 64 (no relu)
        f32x4 acc4[2][4];
#pragma unroll
        for (int nt = 0; nt < 4; nt++) {
            float bv = bias4[nt];
#pragma unroll
            for (int t = 0; t < 2; t++) acc4[t][nt] = (f32x4){bv, bv, bv, bv};
#pragma unroll
            for (int kt = 0; kt < 8; kt++) {
                bf16x8 b = *(const bf16x8*)&w4s[(nt * 16 + col) * 264 + kt * 32 + kg * 8];
#pragma unroll
                for (int t = 0; t < 2; t++)
                    acc4[t][nt] = mfma16(a4[t][kt], b, acc4[t][nt]);
            }
        }
#pragma unroll
        for (int t = 0; t < 2; t++) {
#pragma unroll
            for (int nt = 0; nt < 4; nt++)
#pragma unroll
                for (int r = 0; r < 4; r++)
                    bufA[wid][kg * 4 + r][nt * 16 + col] = (__bf16)acc4[t][nt][r];
            int pt_l = lane >> 2;
            int c0 = (lane & 3) * 16;
            int p = tb + t * 16 + pt_l;
            if (p < N_PTS) {
                const uint4* src = (const uint4*)&bufA[wid][pt_l][c0];
                uint4* dst = (uint4*)(h + (long)p * 64 + c0);
                dst[0] = src[0];
                dst[1] = src[1];
            }
        }
    }
}

// ---------------------------------------------------------------------------
// FUSED gather-max + 3x3 maxpool + transpose. The dense 88.5MB grid is never
// materialized: each block computes its 6x34 halo of per-voxel maxima
// directly from (count, list, h) into LDS, then does the separable pool.
// Latency chains broken: counts and point-ids prefetched in parallel passes.
// ---------------------------------------------------------------------------
__global__ __launch_bounds__(256) void pool_gather(
    const unsigned* __restrict__ count, const int* __restrict__ list,
    const unsigned short* __restrict__ h, float* __restrict__ out)
{
    __shared__ unsigned short tile[6 * 34 * 66];  // bf16 voxel maxima, stride 66
    __shared__ int cnts[204];
    __shared__ int pids[204][8];

    const int tid = threadIdx.x;
    const int x0 = blockIdx.x * 4;
    const int y0 = blockIdx.y * 32;
    const int b = blockIdx.z;

    // (a) parallel halo count load
    if (tid < 204) {
        int xx = tid / 34, yy = tid % 34;
        int gxx = x0 - 1 + xx, gyy = y0 - 1 + yy;
        int n = 0;
        if (gxx >= 0 && gxx < GXD && gyy >= 0 && gyy < GYD)
            n = (int)count[(b * GXD + gxx) * GYD + gyy];
        cnts[tid] = n;
    }
    __syncthreads();

    // (b) parallel point-id prefetch (first 8 slots; n>8 handled in (c))
    for (int idx = tid; idx < 204 * 8; idx += 256) {
        int vi = idx >> 3, slot = idx & 7;
        int n = cnts[vi]; if (n > 8) n = 8;
        if (slot < n) {
            int xx = vi / 34, yy = vi % 34;
            int v = (b * GXD + (x0 - 1 + xx)) * GYD + (y0 - 1 + yy);
            pids[vi][slot] = list[v * CAP + slot];
        }
    }
    __syncthreads();

    // (c) per-wave gather-max: lane = channel, 51 voxels per wave
    {
        const int wid = tid >> 6, lane = tid & 63;
#pragma unroll 1
        for (int i = 0; i < 51; i++) {
            int vi = wid * 51 + i;
            int xx = vi / 34, yy = vi % 34;
            int gxx = x0 - 1 + xx, gyy = y0 - 1 + yy;
            bool inb = (gxx >= 0 && gxx < GXD && gyy >= 0 && gyy < GYD);
            int n = cnts[vi]; if (n > CAP) n = CAP;
            int n8 = n > 8 ? 8 : n;
            float m = -3.0e38f;
            for (int j = 0; j < n8; j++) {
                int pid = pids[vi][j];
                m = fmaxf(m, bf2f(h[(long)pid * 64 + lane]));
            }
            if (n > 8) {
                int v = (b * GXD + gxx) * GYD + gyy;
                for (int j = 8; j < n; j++) {
                    int pid = list[v * CAP + j];
                    m = fmaxf(m, bf2f(h[(long)pid * 64 + lane]));
                }
            }
            if (inb && n == 0) m = 0.f;
            tile[vi * 66 + lane] = f2bf(m);
        }
    }
    __syncthreads();

    // (d) separable 3x3 max + transpose to [b][c][x][y], fp32 out
    const int y = tid & 31;
    const int cg = tid >> 5;
    const bool yv = (y0 + y) < GYD;
#pragma unroll
    for (int cs = 0; cs < 8; cs++) {
        int c = cg * 8 + cs;
        float rowm[6];
#pragma unroll
        for (int xx = 0; xx < 6; xx++) {
            float e0 = bf2f(tile[(xx * 34 + y) * 66 + c]);
            float e1 = bf2f(tile[(xx * 34 + y + 1) * 66 + c]);
            float e2 = bf2f(tile[(xx * 34 + y + 2) * 66 + c]);
            rowm[xx] = fmaxf(fmaxf(e0, e1), e2);
        }
        if (yv) {
#pragma unroll
            for (int xo = 0; xo < 4; xo++) {
                float m = fmaxf(fmaxf(rowm[xo], rowm[xo + 1]), rowm[xo + 2]);
                out[((long)(b * OUTC + c) * GXD + (x0 + xo)) * GYD + (y0 + y)] = m;
            }
        }
    }
}

extern "C" void kernel_launch(void* const* d_in, const int* in_sizes, int n_in,
                              void* d_out, int out_size, void* d_ws, size_t ws_size,
                              hipStream_t stream)
{
    const float* pt   = (const float*)d_in[0];
    const int* bidx   = (const int*)d_in[1];
    const int* gxp    = (const int*)d_in[2];
    const int* gyp    = (const int*)d_in[3];
    const float* bn0g = (const float*)d_in[4],  *bn0b = (const float*)d_in[5];
    const float* bn0m = (const float*)d_in[6],  *bn0v = (const float*)d_in[7];
    const float* bn1g = (const float*)d_in[8],  *bn1b = (const float*)d_in[9];
    const float* bn1m = (const float*)d_in[10], *bn1v = (const float*)d_in[11];
    const float* bn2g = (const float*)d_in[12], *bn2b = (const float*)d_in[13];
    const float* bn2m = (const float*)d_in[14], *bn2v = (const float*)d_in[15];
    const float* bn3g = (const float*)d_in[16], *bn3b = (const float*)d_in[17];
    const float* bn3m = (const float*)d_in[18], *bn3v = (const float*)d_in[19];
    const float* w1 = (const float*)d_in[20], *bb1 = (const float*)d_in[21];
    const float* w2 = (const float*)d_in[22], *bb2 = (const float*)d_in[23];
    const float* w3 = (const float*)d_in[24], *bb3 = (const float*)d_in[25];
    const float* w4 = (const float*)d_in[26], *bb4 = (const float*)d_in[27];

    char* ws = (char*)d_ws;
    __bf16* W1fT = (__bf16*)ws;              // 2048 elems
    __bf16* W2fT = W1fT + 64 * 32;           // 8192
    __bf16* W3fT = W2fT + 128 * 64;          // 32768
    __bf16* W4T  = W3fT + 256 * 128;         // 16384
    float* Bf = (float*)(ws + 2 * (64 * 32 + 128 * 64 + 256 * 128 + 64 * 256));

    unsigned short* h = (unsigned short*)(ws + 131072);          // 38,400,000 B
    unsigned* count   = (unsigned*)(ws + 38531072);              //  2,764,800 B
    int* list         = (int*)(ws + 41295872);                   // 44,236,800 B

    hipLaunchKernelGGL(fold_kernel, dim3(64), dim3(256), 0, stream,
                       bn0g, bn0b, bn0m, bn0v, bn1g, bn1b, bn1m, bn1v,
                       bn2g, bn2b, bn2m, bn2v, bn3g, bn3b, bn3m, bn3v,
                       w1, bb1, w2, bb2, w3, bb3, w4, bb4,
                       W1fT, W2fT, W3fT, W4T, Bf);

    hipLaunchKernelGGL(zcount_kernel, dim3(675), dim3(256), 0, stream, (uint4*)count);

    hipLaunchKernelGGL(mlp_store, dim3(256), dim3(512), 0, stream,
                       pt, bidx, gxp, gyp, W1fT, W2fT, W3fT, W4T, Bf,
                       h, count, list);

    hipLaunchKernelGGL(pool_gather, dim3(GXD / 4, (GYD + 31) / 32, NBATCH),
                       dim3(256), 0, stream, count, list, h, (float*)d_out);
}

// Round 7
// 496.184 us; speedup vs baseline: 1.4360x; 1.0200x over previous
//
#include <hip/hip_runtime.h>
#include <hip/hip_bf16.h>

#define N_PTS 300000
#define GXD 480
#define GYD 360
#define NBATCH 4
#define NVOX (NBATCH * GXD * GYD)
#define OUTC 64
#define BN_EPS 1e-5f
#define CAP 16    // per-voxel list capacity (Poisson lambda=0.43 -> max ~8)
#define PPB 1280  // points per block (256 blocks x 1280 = 327680 >= 300000)
#define NITER 5   // PPB / (8 waves * 32 pts)
#define MAXROWS 1024  // per-tile compacted point cap (avg ~88, 99 sigma safe)
#define CHUNK 128

typedef __attribute__((ext_vector_type(8))) __bf16 bf16x8;
typedef __attribute__((ext_vector_type(4))) float f32x4;

__device__ __forceinline__ f32x4 mfma16(bf16x8 a, bf16x8 b, f32x4 c) {
    return __builtin_amdgcn_mfma_f32_16x16x32_bf16(a, b, c, 0, 0, 0);
}

__device__ __forceinline__ float bf2f(unsigned short u) {
    return __uint_as_float(((unsigned)u) << 16);
}
__device__ __forceinline__ unsigned short f2bf(float f) {
    __hip_bfloat16 h = __float2bfloat16(f);
    return *reinterpret_cast<unsigned short*>(&h);
}

// ---------------------------------------------------------------------------
// Merged: zero per-voxel counters + fold BN into weights (one dispatch).
// ---------------------------------------------------------------------------
__global__ __launch_bounds__(256) void init_kernel(
    const float* __restrict__ bn0g, const float* __restrict__ bn0b,
    const float* __restrict__ bn0m, const float* __restrict__ bn0v,
    const float* __restrict__ bn1g, const float* __restrict__ bn1b,
    const float* __restrict__ bn1m, const float* __restrict__ bn1v,
    const float* __restrict__ bn2g, const float* __restrict__ bn2b,
    const float* __restrict__ bn2m, const float* __restrict__ bn2v,
    const float* __restrict__ bn3g, const float* __restrict__ bn3b,
    const float* __restrict__ bn3m, const float* __restrict__ bn3v,
    const float* __restrict__ w1, const float* __restrict__ bb1,
    const float* __restrict__ w2, const float* __restrict__ bb2,
    const float* __restrict__ w3, const float* __restrict__ bb3,
    const float* __restrict__ w4, const float* __restrict__ bb4,
    __bf16* __restrict__ W1fT, __bf16* __restrict__ W2fT,
    __bf16* __restrict__ W3fT, __bf16* __restrict__ W4T,
    float* __restrict__ Bf, uint4* __restrict__ count4)
{
    // zero counters: 691200 u32 = 172800 uint4 = 675 blocks * 256
    count4[blockIdx.x * 256 + threadIdx.x] = make_uint4(0u, 0u, 0u, 0u);

    const int tid = blockIdx.x * blockDim.x + threadIdx.x;
    const int nth = gridDim.x * blockDim.x;

    for (int i = tid; i < 64 * 32; i += nth) {
        int n = i >> 5, k = i & 31;
        float v = 0.f;
        if (k < 9) {
            float s0 = bn0g[k] * rsqrtf(bn0v[k] + BN_EPS);
            float s1 = bn1g[n] * rsqrtf(bn1v[n] + BN_EPS);
            v = s0 * w1[k * 64 + n] * s1;
        }
        W1fT[i] = (__bf16)v;
    }
    for (int n = tid; n < 64; n += nth) {
        float s1 = bn1g[n] * rsqrtf(bn1v[n] + BN_EPS);
        float t1 = bn1b[n] - bn1m[n] * s1;
        float dot = 0.f;
        for (int k = 0; k < 9; k++) {
            float s0 = bn0g[k] * rsqrtf(bn0v[k] + BN_EPS);
            float t0 = bn0b[k] - bn0m[k] * s0;
            dot += t0 * w1[k * 64 + n];
        }
        Bf[n] = (dot + bb1[n]) * s1 + t1;
    }
    for (int i = tid; i < 128 * 64; i += nth) {
        int n = i >> 6, k = i & 63;
        float s2 = bn2g[n] * rsqrtf(bn2v[n] + BN_EPS);
        W2fT[i] = (__bf16)(w2[k * 128 + n] * s2);
    }
    for (int n = tid; n < 128; n += nth) {
        float s2 = bn2g[n] * rsqrtf(bn2v[n] + BN_EPS);
        Bf[64 + n] = bb2[n] * s2 + (bn2b[n] - bn2m[n] * s2);
    }
    for (int i = tid; i < 256 * 128; i += nth) {
        int n = i >> 7, k = i & 127;
        float s3 = bn3g[n] * rsqrtf(bn3v[n] + BN_EPS);
        W3fT[i] = (__bf16)(w3[k * 256 + n] * s3);
    }
    for (int n = tid; n < 256; n += nth) {
        float s3 = bn3g[n] * rsqrtf(bn3v[n] + BN_EPS);
        Bf[192 + n] = bb3[n] * s3 + (bn3b[n] - bn3m[n] * s3);
    }
    for (int i = tid; i < 64 * 256; i += nth) {
        int n = i >> 8, k = i & 255;
        W4T[i] = (__bf16)w4[k * 64 + n];
    }
    for (int n = tid; n < 64; n += nth) Bf[448 + n] = bb4[n];
}

// ---------------------------------------------------------------------------
// Fused MLP (unchanged from round 6): weights in LDS once per block;
// 512 threads = 8 waves = 2/SIMD; dual 16-pt tiles per wave.
// ---------------------------------------------------------------------------
__global__ __launch_bounds__(512, 2) void mlp_store(
    const float* __restrict__ x, const int* __restrict__ bidx,
    const int* __restrict__ gx, const int* __restrict__ gy,
    const __bf16* __restrict__ W1, const __bf16* __restrict__ W2,
    const __bf16* __restrict__ W3, const __bf16* __restrict__ W4,
    const float* __restrict__ Bf, unsigned short* __restrict__ h,
    unsigned* __restrict__ count, int* __restrict__ list)
{
    __shared__ __bf16 w1s[64 * 40];
    __shared__ __bf16 w2s[128 * 72];
    __shared__ __bf16 w3s[256 * 136];
    __shared__ __bf16 w4s[64 * 264];
    __shared__ __align__(16) __bf16 bufA[8][16][136];

    const int tid = threadIdx.x;
    const int wid = tid >> 6, lane = tid & 63;
    const int col = lane & 15, kg = lane >> 4;

    {
        const uint4* g1 = (const uint4*)W1;
        for (int i = tid; i < 64 * 4; i += 512) {
            int r = i >> 2, q = i & 3;
            *(uint4*)&w1s[r * 40 + q * 8] = g1[r * 4 + q];
        }
        const uint4* g2 = (const uint4*)W2;
        for (int i = tid; i < 128 * 8; i += 512) {
            int r = i >> 3, q = i & 7;
            *(uint4*)&w2s[r * 72 + q * 8] = g2[r * 8 + q];
        }
        const uint4* g3 = (const uint4*)W3;
        for (int i = tid; i < 256 * 16; i += 512) {
            int r = i >> 4, q = i & 15;
            *(uint4*)&w3s[r * 136 + q * 8] = g3[r * 16 + q];
        }
        const uint4* g4 = (const uint4*)W4;
        for (int i = tid; i < 64 * 32; i += 512) {
            int r = i >> 5, q = i & 31;
            *(uint4*)&w4s[r * 264 + q * 8] = g4[r * 32 + q];
        }
    }

    float bias1[4], bias2[8], bias3[16], bias4[4];
#pragma unroll
    for (int i = 0; i < 4; i++) bias1[i] = Bf[i * 16 + col];
#pragma unroll
    for (int i = 0; i < 8; i++) bias2[i] = Bf[64 + i * 16 + col];
#pragma unroll
    for (int i = 0; i < 16; i++) bias3[i] = Bf[192 + i * 16 + col];
#pragma unroll
    for (int i = 0; i < 4; i++) bias4[i] = Bf[448 + i * 16 + col];

    __syncthreads();

    const int blkBase = blockIdx.x * PPB;

#pragma unroll 1
    for (int it = 0; it < NITER; it++) {
        const int tb = blkBase + it * 256 + wid * 32;
        if (tb >= N_PTS) break;

        if (lane < 32) {
            int p = tb + lane;
            if (p < N_PTS) {
                int v = (bidx[p] * GXD + gx[p]) * GYD + gy[p];
                unsigned slot = atomicAdd(count + v, 1u);
                if (slot < CAP) list[v * CAP + slot] = p;
            }
        }

        // ---- L1
        bf16x8 a1[2];
#pragma unroll
        for (int t = 0; t < 2; t++) {
#pragma unroll
            for (int j = 0; j < 8; j++) a1[t][j] = (__bf16)0.f;
            int p0 = tb + t * 16 + col;
            if (p0 < N_PTS) {
                const float* xp = x + (long)p0 * 9;
#pragma unroll
                for (int j = 0; j < 8; j++) {
                    int k = kg * 8 + j;
                    if (k < 9) a1[t][j] = (__bf16)xp[k];
                }
            }
        }
        f32x4 acc1[2][4];
#pragma unroll
        for (int nt = 0; nt < 4; nt++) {
            bf16x8 b = *(const bf16x8*)&w1s[(nt * 16 + col) * 40 + kg * 8];
            float bv = bias1[nt];
#pragma unroll
            for (int t = 0; t < 2; t++)
                acc1[t][nt] = mfma16(a1[t], b, (f32x4){bv, bv, bv, bv});
        }
        bf16x8 a2[2][2];
#pragma unroll
        for (int t = 0; t < 2; t++) {
#pragma unroll
            for (int nt = 0; nt < 4; nt++)
#pragma unroll
                for (int r = 0; r < 4; r++) {
                    float v = acc1[t][nt][r];
                    bufA[wid][kg * 4 + r][nt * 16 + col] = (__bf16)(v > 0.f ? v : 0.f);
                }
#pragma unroll
            for (int kt = 0; kt < 2; kt++)
                a2[t][kt] = *(const bf16x8*)&bufA[wid][col][kt * 32 + kg * 8];
        }

        // ---- L2
        f32x4 acc2[2][8];
#pragma unroll
        for (int nt = 0; nt < 8; nt++) {
            float bv = bias2[nt];
#pragma unroll
            for (int t = 0; t < 2; t++) acc2[t][nt] = (f32x4){bv, bv, bv, bv};
#pragma unroll
            for (int kt = 0; kt < 2; kt++) {
                bf16x8 b = *(const bf16x8*)&w2s[(nt * 16 + col) * 72 + kt * 32 + kg * 8];
#pragma unroll
                for (int t = 0; t < 2; t++)
                    acc2[t][nt] = mfma16(a2[t][kt], b, acc2[t][nt]);
            }
        }
        bf16x8 a3[2][4];
#pragma unroll
        for (int t = 0; t < 2; t++) {
#pragma unroll
            for (int nt = 0; nt < 8; nt++)
#pragma unroll
                for (int r = 0; r < 4; r++) {
                    float v = acc2[t][nt][r];
                    bufA[wid][kg * 4 + r][nt * 16 + col] = (__bf16)(v > 0.f ? v : 0.f);
                }
#pragma unroll
            for (int kt = 0; kt < 4; kt++)
                a3[t][kt] = *(const bf16x8*)&bufA[wid][col][kt * 32 + kg * 8];
        }

        // ---- L3
        f32x4 acc3[2][16];
#pragma unroll
        for (int nt = 0; nt < 16; nt++) {
            float bv = bias3[nt];
#pragma unroll
            for (int t = 0; t < 2; t++) acc3[t][nt] = (f32x4){bv, bv, bv, bv};
#pragma unroll
            for (int kt = 0; kt < 4; kt++) {
                bf16x8 b = *(const bf16x8*)&w3s[(nt * 16 + col) * 136 + kt * 32 + kg * 8];
#pragma unroll
                for (int t = 0; t < 2; t++)
                    acc3[t][nt] = mfma16(a3[t][kt], b, acc3[t][nt]);
            }
        }
        bf16x8 a4[2][8];
#pragma unroll
        for (int t = 0; t < 2; t++) {
#pragma unroll
            for (int nt = 0; nt < 8; nt++)
#pragma unroll
                for (int r = 0; r < 4; r++) {
                    float v = acc3[t][nt][r];
                    bufA[wid][kg * 4 + r][nt * 16 + col] = (__bf16)(v > 0.f ? v : 0.f);
                }
#pragma unroll
            for (int kt = 0; kt < 4; kt++)
                a4[t][kt] = *(const bf16x8*)&bufA[wid][col][kt * 32 + kg * 8];
#pragma unroll
            for (int nt = 8; nt < 16; nt++)
#pragma unroll
                for (int r = 0; r < 4; r++) {
                    float v = acc3[t][nt][r];
                    bufA[wid][kg * 4 + r][(nt - 8) * 16 + col] = (__bf16)(v > 0.f ? v : 0.f);
                }
#pragma unroll
            for (int kt = 4; kt < 8; kt++)
                a4[t][kt] = *(const bf16x8*)&bufA[wid][col][(kt - 4) * 32 + kg * 8];
        }

        // ---- L4
        f32x4 acc4[2][4];
#pragma unroll
        for (int nt = 0; nt < 4; nt++) {
            float bv = bias4[nt];
#pragma unroll
            for (int t = 0; t < 2; t++) acc4[t][nt] = (f32x4){bv, bv, bv, bv};
#pragma unroll
            for (int kt = 0; kt < 8; kt++) {
                bf16x8 b = *(const bf16x8*)&w4s[(nt * 16 + col) * 264 + kt * 32 + kg * 8];
#pragma unroll
                for (int t = 0; t < 2; t++)
                    acc4[t][nt] = mfma16(a4[t][kt], b, acc4[t][nt]);
            }
        }
#pragma unroll
        for (int t = 0; t < 2; t++) {
#pragma unroll
            for (int nt = 0; nt < 4; nt++)
#pragma unroll
                for (int r = 0; r < 4; r++)
                    bufA[wid][kg * 4 + r][nt * 16 + col] = (__bf16)acc4[t][nt][r];
            int pt_l = lane >> 2;
            int c0 = (lane & 3) * 16;
            int p = tb + t * 16 + pt_l;
            if (p < N_PTS) {
                const uint4* src = (const uint4*)&bufA[wid][pt_l][c0];
                uint4* dst = (uint4*)(h + (long)p * 64 + c0);
                dst[0] = src[0];
                dst[1] = src[1];
            }
        }
    }
}

// ---------------------------------------------------------------------------
// FUSED gather-max + 3x3 maxpool + transpose, v2: batched parallel row loads.
// (a) halo counts -> LDS, (b) wave prefix-sum -> offsets, (c) compact pid
// list, (d) cooperative row-load (8 thr x 16B per row, independent loads),
// (e) per-wave max from LDS, (f) empty/OOB fix, (g) separable 3x3 pool.
// LDS ~49 KB -> 3 blocks/CU.
// ---------------------------------------------------------------------------
__global__ __launch_bounds__(256) void pool_gather(
    const unsigned* __restrict__ count, const int* __restrict__ list,
    const unsigned short* __restrict__ h, float* __restrict__ out)
{
    __shared__ unsigned short tile[204 * 66];     // 26,928 B
    __shared__ int cnts[204];
    __shared__ int offs[205];
    __shared__ int pids[MAXROWS];                 // 4,096 B
    __shared__ unsigned short rowbuf[CHUNK][64];  // 16,384 B

    const int tid = threadIdx.x;
    const int wid = tid >> 6, lane = tid & 63;
    const int x0 = blockIdx.x * 4;
    const int y0 = blockIdx.y * 32;
    const int b = blockIdx.z;

    // (a) halo counts
    if (tid < 204) {
        int xx = tid / 34, yy = tid % 34;
        int gxx = x0 - 1 + xx, gyy = y0 - 1 + yy;
        int n = 0;
        if (gxx >= 0 && gxx < GXD && gyy >= 0 && gyy < GYD) {
            n = (int)count[(b * GXD + gxx) * GYD + gyy];
            if (n > CAP) n = CAP;
        }
        cnts[tid] = n;
    }
    __syncthreads();

    // (b) prefix sum (wave 0)
    if (wid == 0) {
        int carry = 0;
        for (int base = 0; base < 204; base += 64) {
            int idx = base + lane;
            int v = (idx < 204) ? cnts[idx] : 0;
#pragma unroll
            for (int d = 1; d < 64; d <<= 1) {
                int t = __shfl_up(v, d);
                if (lane >= d) v += t;
            }
            if (idx < 204) offs[idx + 1] = carry + v;
            carry += __shfl(v, 63);
        }
        if (lane == 0) offs[0] = 0;
    }
    __syncthreads();

    // (c) compact pid list (204 parallel threads, 0-3 loads each)
    if (tid < 204) {
        int n = cnts[tid];
        if (n > 0) {
            int xx = tid / 34, yy = tid % 34;
            int v = (b * GXD + (x0 - 1 + xx)) * GYD + (y0 - 1 + yy);
            int o = offs[tid];
            for (int j = 0; j < n; j++)
                if (o + j < MAXROWS) pids[o + j] = list[v * CAP + j];
        }
    }
    __syncthreads();

    int T = offs[204];
    if (T > MAXROWS) T = MAXROWS;

    // (d)+(e) chunked: batched row load -> LDS, then per-wave max
    for (int c0 = 0; c0 < T; c0 += CHUNK) {
        int R = T - c0; if (R > CHUNK) R = CHUNK;
        for (int r = tid >> 3; r < R; r += 32) {
            int pid = pids[c0 + r];
            *(uint4*)&rowbuf[r][(tid & 7) * 8] =
                *(const uint4*)(h + (long)pid * 64 + (tid & 7) * 8);
        }
        __syncthreads();
#pragma unroll 1
        for (int i = 0; i < 51; i++) {
            int vi = wid * 51 + i;
            int lo = offs[vi], hi = offs[vi + 1];
            if (lo < c0) lo = c0;
            if (hi > c0 + R) hi = c0 + R;
            float m = (c0 == 0) ? -3.0e38f : bf2f(tile[vi * 66 + lane]);
            for (int r = lo; r < hi; r++)
                m = fmaxf(m, bf2f(rowbuf[r - c0][lane]));
            tile[vi * 66 + lane] = f2bf(m);
        }
        __syncthreads();
    }

    // (f) empty / OOB voxels (covers T==0 too)
#pragma unroll 1
    for (int i = 0; i < 51; i++) {
        int vi = wid * 51 + i;
        if (cnts[vi] == 0) {
            int xx = vi / 34, yy = vi % 34;
            int gxx = x0 - 1 + xx, gyy = y0 - 1 + yy;
            bool inb = (gxx >= 0 && gxx < GXD && gyy >= 0 && gyy < GYD);
            tile[vi * 66 + lane] = inb ? (unsigned short)0 : f2bf(-3.0e38f);
        }
    }
    __syncthreads();

    // (g) separable 3x3 max + transpose, fp32 out
    const int y = tid & 31;
    const int cg = tid >> 5;
    const bool yv = (y0 + y) < GYD;
#pragma unroll
    for (int cs = 0; cs < 8; cs++) {
        int c = cg * 8 + cs;
        float rowm[6];
#pragma unroll
        for (int xx = 0; xx < 6; xx++) {
            float e0 = bf2f(tile[(xx * 34 + y) * 66 + c]);
            float e1 = bf2f(tile[(xx * 34 + y + 1) * 66 + c]);
            float e2 = bf2f(tile[(xx * 34 + y + 2) * 66 + c]);
            rowm[xx] = fmaxf(fmaxf(e0, e1), e2);
        }
        if (yv) {
#pragma unroll
            for (int xo = 0; xo < 4; xo++) {
                float m = fmaxf(fmaxf(rowm[xo], rowm[xo + 1]), rowm[xo + 2]);
                out[((long)(b * OUTC + c) * GXD + (x0 + xo)) * GYD + (y0 + y)] = m;
            }
        }
    }
}

extern "C" void kernel_launch(void* const* d_in, const int* in_sizes, int n_in,
                              void* d_out, int out_size, void* d_ws, size_t ws_size,
                              hipStream_t stream)
{
    const float* pt   = (const float*)d_in[0];
    const int* bidx   = (const int*)d_in[1];
    const int* gxp    = (const int*)d_in[2];
    const int* gyp    = (const int*)d_in[3];
    const float* bn0g = (const float*)d_in[4],  *bn0b = (const float*)d_in[5];
    const float* bn0m = (const float*)d_in[6],  *bn0v = (const float*)d_in[7];
    const float* bn1g = (const float*)d_in[8],  *bn1b = (const float*)d_in[9];
    const float* bn1m = (const float*)d_in[10], *bn1v = (const float*)d_in[11];
    const float* bn2g = (const float*)d_in[12], *bn2b = (const float*)d_in[13];
    const float* bn2m = (const float*)d_in[14], *bn2v = (const float*)d_in[15];
    const float* bn3g = (const float*)d_in[16], *bn3b = (const float*)d_in[17];
    const float* bn3m = (const float*)d_in[18], *bn3v = (const float*)d_in[19];
    const float* w1 = (const float*)d_in[20], *bb1 = (const float*)d_in[21];
    const float* w2 = (const float*)d_in[22], *bb2 = (const float*)d_in[23];
    const float* w3 = (const float*)d_in[24], *bb3 = (const float*)d_in[25];
    const float* w4 = (const float*)d_in[26], *bb4 = (const float*)d_in[27];

    char* ws = (char*)d_ws;
    __bf16* W1fT = (__bf16*)ws;
    __bf16* W2fT = W1fT + 64 * 32;
    __bf16* W3fT = W2fT + 128 * 64;
    __bf16* W4T  = W3fT + 256 * 128;
    float* Bf = (float*)(ws + 2 * (64 * 32 + 128 * 64 + 256 * 128 + 64 * 256));

    unsigned short* h = (unsigned short*)(ws + 131072);          // 38,400,000 B
    unsigned* count   = (unsigned*)(ws + 38531072);              //  2,764,800 B
    int* list         = (int*)(ws + 41295872);                   // 44,236,800 B

    hipLaunchKernelGGL(init_kernel, dim3(675), dim3(256), 0, stream,
                       bn0g, bn0b, bn0m, bn0v, bn1g, bn1b, bn1m, bn1v,
                       bn2g, bn2b, bn2m, bn2v, bn3g, bn3b, bn3m, bn3v,
                       w1, bb1, w2, bb2, w3, bb3, w4, bb4,
                       W1fT, W2fT, W3fT, W4T, Bf, (uint4*)count);

    hipLaunchKernelGGL(mlp_store, dim3(256), dim3(512), 0, stream,
                       pt, bidx, gxp, gyp, W1fT, W2fT, W3fT, W4T, Bf,
                       h, count, list);

    hipLaunchKernelGGL(pool_gather, dim3(GXD / 4, (GYD + 31) / 32, NBATCH),
                       dim3(256), 0, stream, count, list, h, (float*)d_out);
}

// Round 8
// 435.578 us; speedup vs baseline: 1.6358x; 1.1391x over previous
//
#include <hip/hip_runtime.h>
#include <hip/hip_bf16.h>

#define N_PTS 300000
#define GXD 480
#define GYD 360
#define NBATCH 4
#define NVOX (NBATCH * GXD * GYD)
#define OUTC 64
#define BN_EPS 1e-5f
#define CAP 16     // per-voxel list capacity (Poisson lambda=0.43 -> max ~8)
#define PPB 1536   // points per block (256 blocks x 1536 = 393216 >= 300000)
#define NITER 4    // PPB / (12 waves * 32 pts)
// pool geometry: 8x x 32y tile, halo 10 x 34
#define HX 10
#define HY 34
#define NHALO (HX * HY)   // 340
#define MAXR 512
#define CHUNK 128

typedef __attribute__((ext_vector_type(8))) __bf16 bf16x8;
typedef __attribute__((ext_vector_type(4))) float f32x4;

__device__ __forceinline__ f32x4 mfma16(bf16x8 a, bf16x8 b, f32x4 c) {
    return __builtin_amdgcn_mfma_f32_16x16x32_bf16(a, b, c, 0, 0, 0);
}

__device__ __forceinline__ float bf2f(unsigned short u) {
    return __uint_as_float(((unsigned)u) << 16);
}
__device__ __forceinline__ unsigned short f2bf(float f) {
    __hip_bfloat16 h = __float2bfloat16(f);
    return *reinterpret_cast<unsigned short*>(&h);
}

__device__ __forceinline__ unsigned cvtpk(float lo, float hi) {
    unsigned r;
    asm("v_cvt_pk_bf16_f32 %0, %1, %2" : "=v"(r) : "v"(lo), "v"(hi));
    return r;
}

__device__ __forceinline__ bf16x8 mkfrag(unsigned a, unsigned b, unsigned c, unsigned d) {
    union { unsigned u[4]; bf16x8 v; } x;
    x.u[0] = a; x.u[1] = b; x.u[2] = c; x.u[3] = d;
    return x.v;
}

// k-slot permutation: slot(kt,g,j) holds input-channel 32kt+16(j>>2)+4g+(j&3).
__device__ __forceinline__ int kperm(int k) {
    return (k & ~31) | (((k >> 2) & 1) << 4) | (((k >> 3) & 3) << 2) | (k & 3);
}

// ---------------------------------------------------------------------------
// Merged init: zero voxel counters + fold BN into weights. W2/W3/W4 staged
// with the k-slot permutation (W1 identity: its K input comes raw from x).
// ---------------------------------------------------------------------------
__global__ __launch_bounds__(256) void init_kernel(
    const float* __restrict__ bn0g, const float* __restrict__ bn0b,
    const float* __restrict__ bn0m, const float* __restrict__ bn0v,
    const float* __restrict__ bn1g, const float* __restrict__ bn1b,
    const float* __restrict__ bn1m, const float* __restrict__ bn1v,
    const float* __restrict__ bn2g, const float* __restrict__ bn2b,
    const float* __restrict__ bn2m, const float* __restrict__ bn2v,
    const float* __restrict__ bn3g, const float* __restrict__ bn3b,
    const float* __restrict__ bn3m, const float* __restrict__ bn3v,
    const float* __restrict__ w1, const float* __restrict__ bb1,
    const float* __restrict__ w2, const float* __restrict__ bb2,
    const float* __restrict__ w3, const float* __restrict__ bb3,
    const float* __restrict__ w4, const float* __restrict__ bb4,
    __bf16* __restrict__ W1fT, __bf16* __restrict__ W2fT,
    __bf16* __restrict__ W3fT, __bf16* __restrict__ W4T,
    float* __restrict__ Bf, uint4* __restrict__ count4)
{
    count4[blockIdx.x * 256 + threadIdx.x] = make_uint4(0u, 0u, 0u, 0u);

    const int tid = blockIdx.x * blockDim.x + threadIdx.x;
    const int nth = gridDim.x * blockDim.x;

    // W1fT [64][32] identity k-map (k<9 real, else 0)
    for (int i = tid; i < 64 * 32; i += nth) {
        int n = i >> 5, k = i & 31;
        float v = 0.f;
        if (k < 9) {
            float s0 = bn0g[k] * rsqrtf(bn0v[k] + BN_EPS);
            float s1 = bn1g[n] * rsqrtf(bn1v[n] + BN_EPS);
            v = s0 * w1[k * 64 + n] * s1;
        }
        W1fT[i] = (__bf16)v;
    }
    for (int n = tid; n < 64; n += nth) {
        float s1 = bn1g[n] * rsqrtf(bn1v[n] + BN_EPS);
        float t1 = bn1b[n] - bn1m[n] * s1;
        float dot = 0.f;
        for (int k = 0; k < 9; k++) {
            float s0 = bn0g[k] * rsqrtf(bn0v[k] + BN_EPS);
            float t0 = bn0b[k] - bn0m[k] * s0;
            dot += t0 * w1[k * 64 + n];
        }
        Bf[n] = (dot + bb1[n]) * s1 + t1;
    }
    // W2fT [128][64] permuted k
    for (int i = tid; i < 128 * 64; i += nth) {
        int n = i >> 6, k = i & 63;
        int ch = kperm(k);
        float s2 = bn2g[n] * rsqrtf(bn2v[n] + BN_EPS);
        W2fT[i] = (__bf16)(w2[ch * 128 + n] * s2);
    }
    for (int n = tid; n < 128; n += nth) {
        float s2 = bn2g[n] * rsqrtf(bn2v[n] + BN_EPS);
        Bf[64 + n] = bb2[n] * s2 + (bn2b[n] - bn2m[n] * s2);
    }
    // W3fT [256][128] permuted k
    for (int i = tid; i < 256 * 128; i += nth) {
        int n = i >> 7, k = i & 127;
        int ch = kperm(k);
        float s3 = bn3g[n] * rsqrtf(bn3v[n] + BN_EPS);
        W3fT[i] = (__bf16)(w3[ch * 256 + n] * s3);
    }
    for (int n = tid; n < 256; n += nth) {
        float s3 = bn3g[n] * rsqrtf(bn3v[n] + BN_EPS);
        Bf[192 + n] = bb3[n] * s3 + (bn3b[n] - bn3m[n] * s3);
    }
    // W4T [64][256] permuted k
    for (int i = tid; i < 64 * 256; i += nth) {
        int n = i >> 8, k = i & 255;
        int ch = kperm(k);
        W4T[i] = (__bf16)w4[ch * 64 + n];
    }
    for (int n = tid; n < 64; n += nth) Bf[448 + n] = bb4[n];
}

// ---------------------------------------------------------------------------
// Fused MLP v3: swapped-operand MFMA + k-permuted weights => activations stay
// in registers (cvt_pk packed accumulators ARE the next layer's fragments).
// No LDS transposes. 768 threads = 12 waves = 3/SIMD. L3+L4 fused to cap
// register pressure (~110 VGPR target, must be <=170 for 3/SIMD).
// LDS: 126,976 weights + 2,048 bias + 27,648 h-repack = 156,672.
// ---------------------------------------------------------------------------
__global__ __launch_bounds__(768, 3) void mlp_store(
    const float* __restrict__ x, const int* __restrict__ bidx,
    const int* __restrict__ gx, const int* __restrict__ gy,
    const __bf16* __restrict__ W1, const __bf16* __restrict__ W2,
    const __bf16* __restrict__ W3, const __bf16* __restrict__ W4,
    const float* __restrict__ Bf, unsigned short* __restrict__ h,
    unsigned* __restrict__ count, int* __restrict__ list)
{
    __shared__ __bf16 w1s[64 * 40];
    __shared__ __bf16 w2s[128 * 72];
    __shared__ __bf16 w3s[256 * 136];
    __shared__ __bf16 w4s[64 * 264];
    __shared__ __align__(16) float biasLds[512];
    __shared__ __align__(16) __bf16 bufA[12][16][72];

    const int tid = threadIdx.x;
    const int wid = tid >> 6, lane = tid & 63;
    const int col = lane & 15, g = lane >> 4;

    // ---- stage weights + biases (once per block)
    {
        const uint4* g1 = (const uint4*)W1;
        for (int i = tid; i < 64 * 4; i += 768) {
            int r = i >> 2, q = i & 3;
            *(uint4*)&w1s[r * 40 + q * 8] = g1[r * 4 + q];
        }
        const uint4* g2 = (const uint4*)W2;
        for (int i = tid; i < 128 * 8; i += 768) {
            int r = i >> 3, q = i & 7;
            *(uint4*)&w2s[r * 72 + q * 8] = g2[r * 8 + q];
        }
        const uint4* g3 = (const uint4*)W3;
        for (int i = tid; i < 256 * 16; i += 768) {
            int r = i >> 4, q = i & 15;
            *(uint4*)&w3s[r * 136 + q * 8] = g3[r * 16 + q];
        }
        const uint4* g4 = (const uint4*)W4;
        for (int i = tid; i < 64 * 32; i += 768) {
            int r = i >> 5, q = i & 31;
            *(uint4*)&w4s[r * 264 + q * 8] = g4[r * 32 + q];
        }
        if (tid < 512) biasLds[tid] = Bf[tid];
    }
    __syncthreads();

    const int blkBase = blockIdx.x * PPB;
    const int bgoff = 4 * g;   // bias lane offset

#pragma unroll 1
    for (int it = 0; it < NITER; it++) {
        const int tb = blkBase + it * 384 + wid * 32;
        if (tb >= N_PTS) break;

        // voxel list build: 1 atomic per point
        if (lane < 32) {
            int p = tb + lane;
            if (p < N_PTS) {
                int v = (bidx[p] * GXD + gx[p]) * GYD + gy[p];
                unsigned slot = atomicAdd(count + v, 1u);
                if (slot < CAP) list[v * CAP + slot] = p;
            }
        }

        // ---- L1: x (K=9->32) -> 64. act as B-slot (identity k-map).
        bf16x8 a1[2];
#pragma unroll
        for (int t = 0; t < 2; t++) {
#pragma unroll
            for (int j = 0; j < 8; j++) a1[t][j] = (__bf16)0.f;
            int p0 = tb + t * 16 + col;
            if (p0 < N_PTS) {
                const float* xp = x + (long)p0 * 9;
#pragma unroll
                for (int j = 0; j < 8; j++) {
                    int k = g * 8 + j;
                    if (k < 9) a1[t][j] = (__bf16)xp[k];
                }
            }
        }
        unsigned pk1[2][4][2];
#pragma unroll
        for (int nt = 0; nt < 4; nt++) {
            bf16x8 w = *(const bf16x8*)&w1s[(nt * 16 + col) * 40 + g * 8];
            f32x4 bv = *(const f32x4*)&biasLds[nt * 16 + bgoff];
#pragma unroll
            for (int t = 0; t < 2; t++) {
                f32x4 a = mfma16(w, a1[t], (f32x4){0.f, 0.f, 0.f, 0.f});
                float v0 = fmaxf(a[0] + bv[0], 0.f), v1 = fmaxf(a[1] + bv[1], 0.f);
                float v2 = fmaxf(a[2] + bv[2], 0.f), v3 = fmaxf(a[3] + bv[3], 0.f);
                pk1[t][nt][0] = cvtpk(v0, v1);
                pk1[t][nt][1] = cvtpk(v2, v3);
            }
        }

        // ---- L2: 64 -> 128
        bf16x8 af2[2][2];
#pragma unroll
        for (int t = 0; t < 2; t++)
#pragma unroll
            for (int kt = 0; kt < 2; kt++)
                af2[t][kt] = mkfrag(pk1[t][2 * kt][0], pk1[t][2 * kt][1],
                                    pk1[t][2 * kt + 1][0], pk1[t][2 * kt + 1][1]);
        unsigned pk2[2][8][2];
#pragma unroll
        for (int nt = 0; nt < 8; nt++) {
            bf16x8 w0 = *(const bf16x8*)&w2s[(nt * 16 + col) * 72 + g * 8];
            bf16x8 w1f = *(const bf16x8*)&w2s[(nt * 16 + col) * 72 + 32 + g * 8];
            f32x4 bv = *(const f32x4*)&biasLds[64 + nt * 16 + bgoff];
#pragma unroll
            for (int t = 0; t < 2; t++) {
                f32x4 a = mfma16(w0, af2[t][0], (f32x4){0.f, 0.f, 0.f, 0.f});
                a = mfma16(w1f, af2[t][1], a);
                float v0 = fmaxf(a[0] + bv[0], 0.f), v1 = fmaxf(a[1] + bv[1], 0.f);
                float v2 = fmaxf(a[2] + bv[2], 0.f), v3 = fmaxf(a[3] + bv[3], 0.f);
                pk2[t][nt][0] = cvtpk(v0, v1);
                pk2[t][nt][1] = cvtpk(v2, v3);
            }
        }

        // ---- L3 (128->256) fused with L4 (256->64): stream pk3 pairs into L4.
        bf16x8 af3[2][4];
#pragma unroll
        for (int t = 0; t < 2; t++)
#pragma unroll
            for (int kt = 0; kt < 4; kt++)
                af3[t][kt] = mkfrag(pk2[t][2 * kt][0], pk2[t][2 * kt][1],
                                    pk2[t][2 * kt + 1][0], pk2[t][2 * kt + 1][1]);
        f32x4 acc4[2][4];
#pragma unroll
        for (int t = 0; t < 2; t++)
#pragma unroll
            for (int nt = 0; nt < 4; nt++)
                acc4[t][nt] = (f32x4){0.f, 0.f, 0.f, 0.f};

#pragma unroll
        for (int hf = 0; hf < 8; hf++) {
            unsigned pr[2][2][2];  // [s][t][2]
#pragma unroll
            for (int s = 0; s < 2; s++) {
                int nt3 = hf * 2 + s;
                bf16x8 w0 = *(const bf16x8*)&w3s[(nt3 * 16 + col) * 136 + g * 8];
                bf16x8 w1f = *(const bf16x8*)&w3s[(nt3 * 16 + col) * 136 + 32 + g * 8];
                bf16x8 w2f = *(const bf16x8*)&w3s[(nt3 * 16 + col) * 136 + 64 + g * 8];
                bf16x8 w3f = *(const bf16x8*)&w3s[(nt3 * 16 + col) * 136 + 96 + g * 8];
                f32x4 bv = *(const f32x4*)&biasLds[192 + nt3 * 16 + bgoff];
#pragma unroll
                for (int t = 0; t < 2; t++) {
                    f32x4 a = mfma16(w0, af3[t][0], (f32x4){0.f, 0.f, 0.f, 0.f});
                    a = mfma16(w1f, af3[t][1], a);
                    a = mfma16(w2f, af3[t][2], a);
                    a = mfma16(w3f, af3[t][3], a);
                    float v0 = fmaxf(a[0] + bv[0], 0.f), v1 = fmaxf(a[1] + bv[1], 0.f);
                    float v2 = fmaxf(a[2] + bv[2], 0.f), v3 = fmaxf(a[3] + bv[3], 0.f);
                    pr[s][t][0] = cvtpk(v0, v1);
                    pr[s][t][1] = cvtpk(v2, v3);
                }
            }
            // L4 partial: kt4 = hf
#pragma unroll
            for (int nt = 0; nt < 4; nt++) {
                bf16x8 w4f = *(const bf16x8*)&w4s[(nt * 16 + col) * 264 + hf * 32 + g * 8];
#pragma unroll
                for (int t = 0; t < 2; t++) {
                    bf16x8 af4 = mkfrag(pr[0][t][0], pr[0][t][1], pr[1][t][0], pr[1][t][1]);
                    acc4[t][nt] = mfma16(w4f, af4, acc4[t][nt]);
                }
            }
        }

        // ---- L4 bias (no relu) + pack + coalesced h store via small LDS repack
        f32x4 bv4[4];
#pragma unroll
        for (int nt = 0; nt < 4; nt++)
            bv4[nt] = *(const f32x4*)&biasLds[448 + nt * 16 + bgoff];
#pragma unroll
        for (int t = 0; t < 2; t++) {
#pragma unroll
            for (int nt = 0; nt < 4; nt++) {
                f32x4 a = acc4[t][nt];
                unsigned lo = cvtpk(a[0] + bv4[nt][0], a[1] + bv4[nt][1]);
                unsigned hi = cvtpk(a[2] + bv4[nt][2], a[3] + bv4[nt][3]);
                *(uint2*)&bufA[wid][col][16 * nt + 4 * g] = make_uint2(lo, hi);
            }
            int pt_l = lane >> 2;
            int c0 = (lane & 3) * 16;
            int p = tb + t * 16 + pt_l;
            if (p < N_PTS) {
                const uint4* src = (const uint4*)&bufA[wid][pt_l][c0];
                uint4* dst = (uint4*)(h + (long)p * 64 + c0);
                dst[0] = src[0];
                dst[1] = src[1];
            }
        }
    }
}

// ---------------------------------------------------------------------------
// FUSED gather-max + 3x3 maxpool + transpose, v3: 8x x 32y tile (halo 10x34),
// 512 threads. Halo redundancy 1.59x -> 1.33x; per-thread (g) work halved.
// ---------------------------------------------------------------------------
__global__ __launch_bounds__(512) void pool_gather(
    const unsigned* __restrict__ count, const int* __restrict__ list,
    const unsigned short* __restrict__ h, float* __restrict__ out)
{
    __shared__ unsigned short tile[NHALO * 66];   // 44,880 B
    __shared__ int cnts[NHALO];
    __shared__ int offs[NHALO + 1];
    __shared__ int pids[MAXR];
    __shared__ unsigned short rowbuf[CHUNK][64];  // 16,384 B

    const int tid = threadIdx.x;
    const int wid = tid >> 6, lane = tid & 63;
    const int x0 = blockIdx.x * 8;
    const int y0 = blockIdx.y * 32;
    const int b = blockIdx.z;

    // (a) halo counts
    if (tid < NHALO) {
        int xx = tid / HY, yy = tid % HY;
        int gxx = x0 - 1 + xx, gyy = y0 - 1 + yy;
        int n = 0;
        if (gxx >= 0 && gxx < GXD && gyy >= 0 && gyy < GYD) {
            n = (int)count[(b * GXD + gxx) * GYD + gyy];
            if (n > CAP) n = CAP;
        }
        cnts[tid] = n;
    }
    __syncthreads();

    // (b) prefix sum (wave 0)
    if (wid == 0) {
        int carry = 0;
        for (int base = 0; base < NHALO; base += 64) {
            int idx = base + lane;
            int v = (idx < NHALO) ? cnts[idx] : 0;
#pragma unroll
            for (int d = 1; d < 64; d <<= 1) {
                int t = __shfl_up(v, d);
                if (lane >= d) v += t;
            }
            if (idx < NHALO) offs[idx + 1] = carry + v;
            carry += __shfl(v, 63);
        }
        if (lane == 0) offs[0] = 0;
    }
    __syncthreads();

    // (c) compact pid list
    if (tid < NHALO) {
        int n = cnts[tid];
        if (n > 0) {
            int xx = tid / HY, yy = tid % HY;
            int v = (b * GXD + (x0 - 1 + xx)) * GYD + (y0 - 1 + yy);
            int o = offs[tid];
            for (int j = 0; j < n; j++)
                if (o + j < MAXR) pids[o + j] = list[v * CAP + j];
        }
    }
    __syncthreads();

    int T = offs[NHALO];
    if (T > MAXR) T = MAXR;

    // (d)+(e) chunked: batched row load -> LDS, then per-wave max (8 waves)
    for (int c0 = 0; c0 < T; c0 += CHUNK) {
        int R = T - c0; if (R > CHUNK) R = CHUNK;
        for (int r = tid >> 3; r < R; r += 64) {
            int pid = pids[c0 + r];
            *(uint4*)&rowbuf[r][(tid & 7) * 8] =
                *(const uint4*)(h + (long)pid * 64 + (tid & 7) * 8);
        }
        __syncthreads();
#pragma unroll 1
        for (int vi = wid; vi < NHALO; vi += 8) {
            int lo = offs[vi], hi = offs[vi + 1];
            if (lo < c0) lo = c0;
            if (hi > c0 + R) hi = c0 + R;
            float m = (c0 == 0) ? -3.0e38f : bf2f(tile[vi * 66 + lane]);
            for (int r = lo; r < hi; r++)
                m = fmaxf(m, bf2f(rowbuf[r - c0][lane]));
            tile[vi * 66 + lane] = f2bf(m);
        }
        __syncthreads();
    }

    // (f) empty / OOB voxels (covers T==0)
#pragma unroll 1
    for (int vi = wid; vi < NHALO; vi += 8) {
        if (cnts[vi] == 0) {
            int xx = vi / HY, yy = vi % HY;
            int gxx = x0 - 1 + xx, gyy = y0 - 1 + yy;
            bool inb = (gxx >= 0 && gxx < GXD && gyy >= 0 && gyy < GYD);
            tile[vi * 66 + lane] = inb ? (unsigned short)0 : f2bf(-3.0e38f);
        }
    }
    __syncthreads();

    // (g) separable 3x3 max + transpose, fp32 out. 512 thr: y=tid&31,
    // grp=tid>>5: xh=grp>>3 (x-half), cgrp=grp&7 (8-ch group).
    const int y = tid & 31;
    const int grp = tid >> 5;
    const int xh = grp >> 3;
    const int cgrp = grp & 7;
    const bool yv = (y0 + y) < GYD;
#pragma unroll
    for (int cs = 0; cs < 8; cs++) {
        int c = cgrp * 8 + cs;
        float rowm[6];
#pragma unroll
        for (int xx = 0; xx < 6; xx++) {
            int hxx = xh * 4 + xx;
            float e0 = bf2f(tile[(hxx * HY + y) * 66 + c]);
            float e1 = bf2f(tile[(hxx * HY + y + 1) * 66 + c]);
            float e2 = bf2f(tile[(hxx * HY + y + 2) * 66 + c]);
            rowm[xx] = fmaxf(fmaxf(e0, e1), e2);
        }
        if (yv) {
#pragma unroll
            for (int xo = 0; xo < 4; xo++) {
                float m = fmaxf(fmaxf(rowm[xo], rowm[xo + 1]), rowm[xo + 2]);
                int xg = x0 + xh * 4 + xo;
                out[((long)(b * OUTC + c) * GXD + xg) * GYD + (y0 + y)] = m;
            }
        }
    }
}

extern "C" void kernel_launch(void* const* d_in, const int* in_sizes, int n_in,
                              void* d_out, int out_size, void* d_ws, size_t ws_size,
                              hipStream_t stream)
{
    const float* pt   = (const float*)d_in[0];
    const int* bidx   = (const int*)d_in[1];
    const int* gxp    = (const int*)d_in[2];
    const int* gyp    = (const int*)d_in[3];
    const float* bn0g = (const float*)d_in[4],  *bn0b = (const float*)d_in[5];
    const float* bn0m = (const float*)d_in[6],  *bn0v = (const float*)d_in[7];
    const float* bn1g = (const float*)d_in[8],  *bn1b = (const float*)d_in[9];
    const float* bn1m = (const float*)d_in[10], *bn1v = (const float*)d_in[11];
    const float* bn2g = (const float*)d_in[12], *bn2b = (const float*)d_in[13];
    const float* bn2m = (const float*)d_in[14], *bn2v = (const float*)d_in[15];
    const float* bn3g = (const float*)d_in[16], *bn3b = (const float*)d_in[17];
    const float* bn3m = (const float*)d_in[18], *bn3v = (const float*)d_in[19];
    const float* w1 = (const float*)d_in[20], *bb1 = (const float*)d_in[21];
    const float* w2 = (const float*)d_in[22], *bb2 = (const float*)d_in[23];
    const float* w3 = (const float*)d_in[24], *bb3 = (const float*)d_in[25];
    const float* w4 = (const float*)d_in[26], *bb4 = (const float*)d_in[27];

    char* ws = (char*)d_ws;
    __bf16* W1fT = (__bf16*)ws;
    __bf16* W2fT = W1fT + 64 * 32;
    __bf16* W3fT = W2fT + 128 * 64;
    __bf16* W4T  = W3fT + 256 * 128;
    float* Bf = (float*)(ws + 2 * (64 * 32 + 128 * 64 + 256 * 128 + 64 * 256));

    unsigned short* h = (unsigned short*)(ws + 131072);          // 38,400,000 B
    unsigned* count   = (unsigned*)(ws + 38531072);              //  2,764,800 B
    int* list         = (int*)(ws + 41295872);                   // 44,236,800 B

    hipLaunchKernelGGL(init_kernel, dim3(675), dim3(256), 0, stream,
                       bn0g, bn0b, bn0m, bn0v, bn1g, bn1b, bn1m, bn1v,
                       bn2g, bn2b, bn2m, bn2v, bn3g, bn3b, bn3m, bn3v,
                       w1, bb1, w2, bb2, w3, bb3, w4, bb4,
                       W1fT, W2fT, W3fT, W4T, Bf, (uint4*)count);

    hipLaunchKernelGGL(mlp_store, dim3(256), dim3(768), 0, stream,
                       pt, bidx, gxp, gyp, W1fT, W2fT, W3fT, W4T, Bf,
                       h, count, list);

    hipLaunchKernelGGL(pool_gather, dim3(GXD / 8, (GYD + 31) / 32, NBATCH),
                       dim3(512), 0, stream, count, list, h, (float*)d_out);
}

// Round 10
// 394.089 us; speedup vs baseline: 1.8080x; 1.1053x over previous
//
#include <hip/hip_runtime.h>
#include <hip/hip_bf16.h>

#define N_PTS 300000
#define GXD 480
#define GYD 360
#define NBATCH 4
#define NVOX (NBATCH * GXD * GYD)
#define OUTC 64
#define BN_EPS 1e-5f
#define CAP 16     // per-voxel list capacity (Poisson lambda=0.43 -> max ~9)
#define PPB 1536   // points per block (256 blocks x 1536 = 393216 >= 300000)
#define NITER 4    // PPB / (12 waves * 32 pts)
// pool geometry: 8x x 32y tile, halo 10 x 34
#define HX 10
#define HY 34
#define NHALO (HX * HY)   // 340
#define MAXR 256
#define CHUNK 192

typedef __attribute__((ext_vector_type(8))) __bf16 bf16x8;
typedef __attribute__((ext_vector_type(4))) float f32x4;
typedef unsigned short us2 __attribute__((ext_vector_type(2)));

__device__ __forceinline__ f32x4 mfma16(bf16x8 a, bf16x8 b, f32x4 c) {
    return __builtin_amdgcn_mfma_f32_16x16x32_bf16(a, b, c, 0, 0, 0);
}

__device__ __forceinline__ unsigned cvtpk(float lo, float hi) {
    unsigned r;
    asm("v_cvt_pk_bf16_f32 %0, %1, %2" : "=v"(r) : "v"(lo), "v"(hi));
    return r;
}

__device__ __forceinline__ bf16x8 mkfrag(unsigned a, unsigned b, unsigned c, unsigned d) {
    union { unsigned u[4]; bf16x8 v; } x;
    x.u[0] = a; x.u[1] = b; x.u[2] = c; x.u[3] = d;
    return x.v;
}

// order-preserving encode of 2 packed bf16 (per half: pos -> u|0x8000, neg -> ~u)
__device__ __forceinline__ unsigned enc2(unsigned u) {
    return u ^ ((((u >> 15) & 0x00010001u) * 0x7FFFu) | 0x80008000u);
}
__device__ __forceinline__ unsigned dec2(unsigned e) {
    return e ^ (((((~e) >> 15) & 0x00010001u) * 0x7FFFu) | 0x80008000u);
}
// packed u16 max (v_pk_max_u16)
__device__ __forceinline__ unsigned pkmax(unsigned a, unsigned b) {
    union { unsigned u; us2 v; } x, y;
    x.u = a; y.u = b;
    x.v = __builtin_elementwise_max(x.v, y.v);
    return x.u;
}
__device__ __forceinline__ uint4 pkmax4(uint4 a, uint4 b) {
    return make_uint4(pkmax(a.x, b.x), pkmax(a.y, b.y),
                      pkmax(a.z, b.z), pkmax(a.w, b.w));
}

// k-slot permutation: slot(kt,g,j) holds input-channel 32kt+16(j>>2)+4g+(j&3).
__device__ __forceinline__ int kperm(int k) {
    return (k & ~31) | (((k >> 2) & 1) << 4) | (((k >> 3) & 3) << 2) | (k & 3);
}

// ---------------------------------------------------------------------------
// Merged init: zero voxel counters + fold BN into weights (k-permuted).
// ---------------------------------------------------------------------------
__global__ __launch_bounds__(256) void init_kernel(
    const float* __restrict__ bn0g, const float* __restrict__ bn0b,
    const float* __restrict__ bn0m, const float* __restrict__ bn0v,
    const float* __restrict__ bn1g, const float* __restrict__ bn1b,
    const float* __restrict__ bn1m, const float* __restrict__ bn1v,
    const float* __restrict__ bn2g, const float* __restrict__ bn2b,
    const float* __restrict__ bn2m, const float* __restrict__ bn2v,
    const float* __restrict__ bn3g, const float* __restrict__ bn3b,
    const float* __restrict__ bn3m, const float* __restrict__ bn3v,
    const float* __restrict__ w1, const float* __restrict__ bb1,
    const float* __restrict__ w2, const float* __restrict__ bb2,
    const float* __restrict__ w3, const float* __restrict__ bb3,
    const float* __restrict__ w4, const float* __restrict__ bb4,
    __bf16* __restrict__ W1fT, __bf16* __restrict__ W2fT,
    __bf16* __restrict__ W3fT, __bf16* __restrict__ W4T,
    float* __restrict__ Bf, uint4* __restrict__ count4)
{
    count4[blockIdx.x * 256 + threadIdx.x] = make_uint4(0u, 0u, 0u, 0u);

    const int tid = blockIdx.x * blockDim.x + threadIdx.x;
    const int nth = gridDim.x * blockDim.x;

    for (int i = tid; i < 64 * 32; i += nth) {
        int n = i >> 5, k = i & 31;
        float v = 0.f;
        if (k < 9) {
            float s0 = bn0g[k] * rsqrtf(bn0v[k] + BN_EPS);
            float s1 = bn1g[n] * rsqrtf(bn1v[n] + BN_EPS);
            v = s0 * w1[k * 64 + n] * s1;
        }
        W1fT[i] = (__bf16)v;
    }
    for (int n = tid; n < 64; n += nth) {
        float s1 = bn1g[n] * rsqrtf(bn1v[n] + BN_EPS);
        float t1 = bn1b[n] - bn1m[n] * s1;
        float dot = 0.f;
        for (int k = 0; k < 9; k++) {
            float s0 = bn0g[k] * rsqrtf(bn0v[k] + BN_EPS);
            float t0 = bn0b[k] - bn0m[k] * s0;
            dot += t0 * w1[k * 64 + n];
        }
        Bf[n] = (dot + bb1[n]) * s1 + t1;
    }
    for (int i = tid; i < 128 * 64; i += nth) {
        int n = i >> 6, k = i & 63;
        int ch = kperm(k);
        float s2 = bn2g[n] * rsqrtf(bn2v[n] + BN_EPS);
        W2fT[i] = (__bf16)(w2[ch * 128 + n] * s2);
    }
    for (int n = tid; n < 128; n += nth) {
        float s2 = bn2g[n] * rsqrtf(bn2v[n] + BN_EPS);
        Bf[64 + n] = bb2[n] * s2 + (bn2b[n] - bn2m[n] * s2);
    }
    for (int i = tid; i < 256 * 128; i += nth) {
        int n = i >> 7, k = i & 127;
        int ch = kperm(k);
        float s3 = bn3g[n] * rsqrtf(bn3v[n] + BN_EPS);
        W3fT[i] = (__bf16)(w3[ch * 256 + n] * s3);
    }
    for (int n = tid; n < 256; n += nth) {
        float s3 = bn3g[n] * rsqrtf(bn3v[n] + BN_EPS);
        Bf[192 + n] = bb3[n] * s3 + (bn3b[n] - bn3m[n] * s3);
    }
    for (int i = tid; i < 64 * 256; i += nth) {
        int n = i >> 8, k = i & 255;
        int ch = kperm(k);
        W4T[i] = (__bf16)w4[ch * 64 + n];
    }
    for (int n = tid; n < 64; n += nth) Bf[448 + n] = bb4[n];
}

// ---------------------------------------------------------------------------
// Fused MLP v3 (unchanged core): swapped-operand MFMA, register-resident
// activations. Epilogue stores h ENCODED (order-preserving packed u16)
// so the pool can run entirely on packed-u16 max.
// ---------------------------------------------------------------------------
__global__ __launch_bounds__(768, 3) void mlp_store(
    const float* __restrict__ x, const int* __restrict__ bidx,
    const int* __restrict__ gx, const int* __restrict__ gy,
    const __bf16* __restrict__ W1, const __bf16* __restrict__ W2,
    const __bf16* __restrict__ W3, const __bf16* __restrict__ W4,
    const float* __restrict__ Bf, unsigned short* __restrict__ h,
    unsigned* __restrict__ count, int* __restrict__ list)
{
    __shared__ __bf16 w1s[64 * 40];
    __shared__ __bf16 w2s[128 * 72];
    __shared__ __bf16 w3s[256 * 136];
    __shared__ __bf16 w4s[64 * 264];
    __shared__ __align__(16) float biasLds[512];
    __shared__ __align__(16) __bf16 bufA[12][16][72];

    const int tid = threadIdx.x;
    const int wid = tid >> 6, lane = tid & 63;
    const int col = lane & 15, g = lane >> 4;

    {
        const uint4* g1 = (const uint4*)W1;
        for (int i = tid; i < 64 * 4; i += 768) {
            int r = i >> 2, q = i & 3;
            *(uint4*)&w1s[r * 40 + q * 8] = g1[r * 4 + q];
        }
        const uint4* g2 = (const uint4*)W2;
        for (int i = tid; i < 128 * 8; i += 768) {
            int r = i >> 3, q = i & 7;
            *(uint4*)&w2s[r * 72 + q * 8] = g2[r * 8 + q];
        }
        const uint4* g3 = (const uint4*)W3;
        for (int i = tid; i < 256 * 16; i += 768) {
            int r = i >> 4, q = i & 15;
            *(uint4*)&w3s[r * 136 + q * 8] = g3[r * 16 + q];
        }
        const uint4* g4 = (const uint4*)W4;
        for (int i = tid; i < 64 * 32; i += 768) {
            int r = i >> 5, q = i & 31;
            *(uint4*)&w4s[r * 264 + q * 8] = g4[r * 32 + q];
        }
        if (tid < 512) biasLds[tid] = Bf[tid];
    }
    __syncthreads();

    const int blkBase = blockIdx.x * PPB;
    const int bgoff = 4 * g;

#pragma unroll 1
    for (int it = 0; it < NITER; it++) {
        const int tb = blkBase + it * 384 + wid * 32;
        if (tb >= N_PTS) break;

        if (lane < 32) {
            int p = tb + lane;
            if (p < N_PTS) {
                int v = (bidx[p] * GXD + gx[p]) * GYD + gy[p];
                unsigned slot = atomicAdd(count + v, 1u);
                if (slot < CAP) list[v * CAP + slot] = p;
            }
        }

        // ---- L1
        bf16x8 a1[2];
#pragma unroll
        for (int t = 0; t < 2; t++) {
#pragma unroll
            for (int j = 0; j < 8; j++) a1[t][j] = (__bf16)0.f;
            int p0 = tb + t * 16 + col;
            if (p0 < N_PTS) {
                const float* xp = x + (long)p0 * 9;
#pragma unroll
                for (int j = 0; j < 8; j++) {
                    int k = g * 8 + j;
                    if (k < 9) a1[t][j] = (__bf16)xp[k];
                }
            }
        }
        unsigned pk1[2][4][2];
#pragma unroll
        for (int nt = 0; nt < 4; nt++) {
            bf16x8 w = *(const bf16x8*)&w1s[(nt * 16 + col) * 40 + g * 8];
            f32x4 bv = *(const f32x4*)&biasLds[nt * 16 + bgoff];
#pragma unroll
            for (int t = 0; t < 2; t++) {
                f32x4 a = mfma16(w, a1[t], (f32x4){0.f, 0.f, 0.f, 0.f});
                float v0 = fmaxf(a[0] + bv[0], 0.f), v1 = fmaxf(a[1] + bv[1], 0.f);
                float v2 = fmaxf(a[2] + bv[2], 0.f), v3 = fmaxf(a[3] + bv[3], 0.f);
                pk1[t][nt][0] = cvtpk(v0, v1);
                pk1[t][nt][1] = cvtpk(v2, v3);
            }
        }

        // ---- L2
        bf16x8 af2[2][2];
#pragma unroll
        for (int t = 0; t < 2; t++)
#pragma unroll
            for (int kt = 0; kt < 2; kt++)
                af2[t][kt] = mkfrag(pk1[t][2 * kt][0], pk1[t][2 * kt][1],
                                    pk1[t][2 * kt + 1][0], pk1[t][2 * kt + 1][1]);
        unsigned pk2[2][8][2];
#pragma unroll
        for (int nt = 0; nt < 8; nt++) {
            bf16x8 w0 = *(const bf16x8*)&w2s[(nt * 16 + col) * 72 + g * 8];
            bf16x8 w1f = *(const bf16x8*)&w2s[(nt * 16 + col) * 72 + 32 + g * 8];
            f32x4 bv = *(const f32x4*)&biasLds[64 + nt * 16 + bgoff];
#pragma unroll
            for (int t = 0; t < 2; t++) {
                f32x4 a = mfma16(w0, af2[t][0], (f32x4){0.f, 0.f, 0.f, 0.f});
                a = mfma16(w1f, af2[t][1], a);
                float v0 = fmaxf(a[0] + bv[0], 0.f), v1 = fmaxf(a[1] + bv[1], 0.f);
                float v2 = fmaxf(a[2] + bv[2], 0.f), v3 = fmaxf(a[3] + bv[3], 0.f);
                pk2[t][nt][0] = cvtpk(v0, v1);
                pk2[t][nt][1] = cvtpk(v2, v3);
            }
        }

        // ---- L3 fused with L4
        bf16x8 af3[2][4];
#pragma unroll
        for (int t = 0; t < 2; t++)
#pragma unroll
            for (int kt = 0; kt < 4; kt++)
                af3[t][kt] = mkfrag(pk2[t][2 * kt][0], pk2[t][2 * kt][1],
                                    pk2[t][2 * kt + 1][0], pk2[t][2 * kt + 1][1]);
        f32x4 acc4[2][4];
#pragma unroll
        for (int t = 0; t < 2; t++)
#pragma unroll
            for (int nt = 0; nt < 4; nt++)
                acc4[t][nt] = (f32x4){0.f, 0.f, 0.f, 0.f};

#pragma unroll
        for (int hf = 0; hf < 8; hf++) {
            unsigned pr[2][2][2];
#pragma unroll
            for (int s = 0; s < 2; s++) {
                int nt3 = hf * 2 + s;
                bf16x8 w0 = *(const bf16x8*)&w3s[(nt3 * 16 + col) * 136 + g * 8];
                bf16x8 w1f = *(const bf16x8*)&w3s[(nt3 * 16 + col) * 136 + 32 + g * 8];
                bf16x8 w2f = *(const bf16x8*)&w3s[(nt3 * 16 + col) * 136 + 64 + g * 8];
                bf16x8 w3f = *(const bf16x8*)&w3s[(nt3 * 16 + col) * 136 + 96 + g * 8];
                f32x4 bv = *(const f32x4*)&biasLds[192 + nt3 * 16 + bgoff];
#pragma unroll
                for (int t = 0; t < 2; t++) {
                    f32x4 a = mfma16(w0, af3[t][0], (f32x4){0.f, 0.f, 0.f, 0.f});
                    a = mfma16(w1f, af3[t][1], a);
                    a = mfma16(w2f, af3[t][2], a);
                    a = mfma16(w3f, af3[t][3], a);
                    float v0 = fmaxf(a[0] + bv[0], 0.f), v1 = fmaxf(a[1] + bv[1], 0.f);
                    float v2 = fmaxf(a[2] + bv[2], 0.f), v3 = fmaxf(a[3] + bv[3], 0.f);
                    pr[s][t][0] = cvtpk(v0, v1);
                    pr[s][t][1] = cvtpk(v2, v3);
                }
            }
#pragma unroll
            for (int nt = 0; nt < 4; nt++) {
                bf16x8 w4f = *(const bf16x8*)&w4s[(nt * 16 + col) * 264 + hf * 32 + g * 8];
#pragma unroll
                for (int t = 0; t < 2; t++) {
                    bf16x8 af4 = mkfrag(pr[0][t][0], pr[0][t][1], pr[1][t][0], pr[1][t][1]);
                    acc4[t][nt] = mfma16(w4f, af4, acc4[t][nt]);
                }
            }
        }

        // ---- L4 bias + pack + ENCODE + coalesced store
        f32x4 bv4[4];
#pragma unroll
        for (int nt = 0; nt < 4; nt++)
            bv4[nt] = *(const f32x4*)&biasLds[448 + nt * 16 + bgoff];
#pragma unroll
        for (int t = 0; t < 2; t++) {
#pragma unroll
            for (int nt = 0; nt < 4; nt++) {
                f32x4 a = acc4[t][nt];
                unsigned lo = enc2(cvtpk(a[0] + bv4[nt][0], a[1] + bv4[nt][1]));
                unsigned hi = enc2(cvtpk(a[2] + bv4[nt][2], a[3] + bv4[nt][3]));
                *(uint2*)&bufA[wid][col][16 * nt + 4 * g] = make_uint2(lo, hi);
            }
            int pt_l = lane >> 2;
            int c0 = (lane & 3) * 16;
            int p = tb + t * 16 + pt_l;
            if (p < N_PTS) {
                const uint4* src = (const uint4*)&bufA[wid][pt_l][c0];
                uint4* dst = (uint4*)(h + (long)p * 64 + c0);
                dst[0] = src[0];
                dst[1] = src[1];
            }
        }
    }
}

// ---------------------------------------------------------------------------
// FUSED gather-max + 3x3 maxpool, v4: entire pipeline in packed-encoded u16
// domain (v_pk_max_u16). Half-wave = 1 voxel in the gather; (g) reads tile
// as b128 (8ch) instead of 144 scalar u16 reads. Decode only at output.
// LDS 77,284 B -> 2 blocks/CU.
// ---------------------------------------------------------------------------
__global__ __launch_bounds__(512) void pool_gather(
    const unsigned* __restrict__ count, const int* __restrict__ list,
    const unsigned short* __restrict__ h, float* __restrict__ out)
{
    __shared__ __align__(16) unsigned tile[NHALO * 36];   // 48,960 B (stride 36 u32)
    __shared__ int cnts[NHALO];
    __shared__ int offs[NHALO + 1];
    __shared__ int pids[MAXR];
    __shared__ __align__(16) unsigned short rowbuf[CHUNK][64];  // 24,576 B

    const int tid = threadIdx.x;
    const int wid = tid >> 6, lane = tid & 63;
    const int lane32 = lane & 31;
    const int vh = (wid << 1) | (lane >> 5);   // half-wave id 0..15
    const int x0 = blockIdx.x * 8;
    const int y0 = blockIdx.y * 32;
    const int b = blockIdx.z;

    // (a) halo counts
    if (tid < NHALO) {
        int xx = tid / HY, yy = tid % HY;
        int gxx = x0 - 1 + xx, gyy = y0 - 1 + yy;
        int n = 0;
        if (gxx >= 0 && gxx < GXD && gyy >= 0 && gyy < GYD) {
            n = (int)count[(b * GXD + gxx) * GYD + gyy];
            if (n > CAP) n = CAP;
        }
        cnts[tid] = n;
    }
    __syncthreads();

    // (b) prefix sum (wave 0)
    if (wid == 0) {
        int carry = 0;
        for (int base = 0; base < NHALO; base += 64) {
            int idx = base + lane;
            int v = (idx < NHALO) ? cnts[idx] : 0;
#pragma unroll
            for (int d = 1; d < 64; d <<= 1) {
                int t = __shfl_up(v, d);
                if (lane >= d) v += t;
            }
            if (idx < NHALO) offs[idx + 1] = carry + v;
            carry += __shfl(v, 63);
        }
        if (lane == 0) offs[0] = 0;
    }
    __syncthreads();

    // (c) compact pid list
    if (tid < NHALO) {
        int n = cnts[tid];
        if (n > 0) {
            int xx = tid / HY, yy = tid % HY;
            int v = (b * GXD + (x0 - 1 + xx)) * GYD + (y0 - 1 + yy);
            int o = offs[tid];
            for (int j = 0; j < n; j++)
                if (o + j < MAXR) pids[o + j] = list[v * CAP + j];
        }
    }
    __syncthreads();

    int T = offs[NHALO];
    if (T > MAXR) T = MAXR;

    // (d)+(e) chunked (single pass when T<=192): batched row load, then
    // half-wave-per-voxel packed max. lane32 = channel-pair (2 ch / u32).
    for (int c0 = 0; c0 < T; c0 += CHUNK) {
        int R = T - c0; if (R > CHUNK) R = CHUNK;
        for (int r = tid >> 3; r < R; r += 64) {
            int pid = pids[c0 + r];
            *(uint4*)&rowbuf[r][(tid & 7) * 8] =
                *(const uint4*)(h + (long)pid * 64 + (tid & 7) * 8);
        }
        __syncthreads();
#pragma unroll 1
        for (int vi = vh; vi < NHALO; vi += 16) {
            int lo = offs[vi], hi = offs[vi + 1];
            int flo = lo;                 // first row overall for this voxel
            if (lo < c0) lo = c0;
            if (hi > c0 + R) hi = c0 + R;
            if (lo >= hi) continue;
            unsigned m = (flo < c0) ? tile[vi * 36 + lane32] : 0u;
            for (int r = lo; r < hi; r++)
                m = pkmax(m, *(const unsigned*)&rowbuf[r - c0][lane32 * 2]);
            tile[vi * 36 + lane32] = m;
        }
        __syncthreads();
    }

    // (f) empty / OOB voxels (half-wave each; covers T==0)
#pragma unroll 1
    for (int vi = vh; vi < NHALO; vi += 16) {
        if (cnts[vi] == 0) {
            int xx = vi / HY, yy = vi % HY;
            int gxx = x0 - 1 + xx, gyy = y0 - 1 + yy;
            bool inb = (gxx >= 0 && gxx < GXD && gyy >= 0 && gyy < GYD);
            tile[vi * 36 + lane32] = inb ? 0x80008000u : 0u;  // enc(0.0) / enc-min
        }
    }
    __syncthreads();

    // (g) separable 3x3 max in encoded domain, b128 tile reads, decode at end.
    const int y = tid & 31;
    const int grp = tid >> 5;
    const int xh = grp >> 3;     // x-half (0..1)
    const int cgrp = grp & 7;    // 8-channel group
    if ((y0 + y) < GYD) {
        uint4 rowm[6];
#pragma unroll
        for (int xx = 0; xx < 6; xx++) {
            int hxx = xh * 4 + xx;
            const uint4* base = (const uint4*)&tile[(hxx * HY + y) * 36 + cgrp * 4];
            uint4 e0 = base[0];
            uint4 e1 = *(const uint4*)&tile[(hxx * HY + y + 1) * 36 + cgrp * 4];
            uint4 e2 = *(const uint4*)&tile[(hxx * HY + y + 2) * 36 + cgrp * 4];
            rowm[xx] = pkmax4(pkmax4(e0, e1), e2);
        }
#pragma unroll
        for (int xo = 0; xo < 4; xo++) {
            uint4 mm = pkmax4(pkmax4(rowm[xo], rowm[xo + 1]), rowm[xo + 2]);
            int xg = x0 + xh * 4 + xo;
            long obase = ((long)(b * OUTC + cgrp * 8) * GXD + xg) * GYD + (y0 + y);
            unsigned dd[4] = {dec2(mm.x), dec2(mm.y), dec2(mm.z), dec2(mm.w)};
#pragma unroll
            for (int j = 0; j < 4; j++) {
                float flo = __uint_as_float(dd[j] << 16);
                float fhi = __uint_as_float(dd[j] & 0xFFFF0000u);
                out[obase + (long)(2 * j) * GXD * GYD] = flo;
                out[obase + (long)(2 * j + 1) * GXD * GYD] = fhi;
            }
        }
    }
}

extern "C" void kernel_launch(void* const* d_in, const int* in_sizes, int n_in,
                              void* d_out, int out_size, void* d_ws, size_t ws_size,
                              hipStream_t stream)
{
    const float* pt   = (const float*)d_in[0];
    const int* bidx   = (const int*)d_in[1];
    const int* gxp    = (const int*)d_in[2];
    const int* gyp    = (const int*)d_in[3];
    const float* bn0g = (const float*)d_in[4],  *bn0b = (const float*)d_in[5];
    const float* bn0m = (const float*)d_in[6],  *bn0v = (const float*)d_in[7];
    const float* bn1g = (const float*)d_in[8],  *bn1b = (const float*)d_in[9];
    const float* bn1m = (const float*)d_in[10], *bn1v = (const float*)d_in[11];
    const float* bn2g = (const float*)d_in[12], *bn2b = (const float*)d_in[13];
    const float* bn2m = (const float*)d_in[14], *bn2v = (const float*)d_in[15];
    const float* bn3g = (const float*)d_in[16], *bn3b = (const float*)d_in[17];
    const float* bn3m = (const float*)d_in[18], *bn3v = (const float*)d_in[19];
    const float* w1 = (const float*)d_in[20], *bb1 = (const float*)d_in[21];
    const float* w2 = (const float*)d_in[22], *bb2 = (const float*)d_in[23];
    const float* w3 = (const float*)d_in[24], *bb3 = (const float*)d_in[25];
    const float* w4 = (const float*)d_in[26], *bb4 = (const float*)d_in[27];

    char* ws = (char*)d_ws;
    __bf16* W1fT = (__bf16*)ws;
    __bf16* W2fT = W1fT + 64 * 32;
    __bf16* W3fT = W2fT + 128 * 64;
    __bf16* W4T  = W3fT + 256 * 128;
    float* Bf = (float*)(ws + 2 * (64 * 32 + 128 * 64 + 256 * 128 + 64 * 256));

    unsigned short* h = (unsigned short*)(ws + 131072);          // 38,400,000 B
    unsigned* count   = (unsigned*)(ws + 38531072);              //  2,764,800 B
    int* list         = (int*)(ws + 41295872);                   // 44,236,800 B

    hipLaunchKernelGGL(init_kernel, dim3(675), dim3(256), 0, stream,
                       bn0g, bn0b, bn0m, bn0v, bn1g, bn1b, bn1m, bn1v,
                       bn2g, bn2b, bn2m, bn2v, bn3g, bn3b, bn3m, bn3v,
                       w1, bb1, w2, bb2, w3, bb3, w4, bb4,
                       W1fT, W2fT, W3fT, W4T, Bf, (uint4*)count);

    hipLaunchKernelGGL(mlp_store, dim3(256), dim3(768), 0, stream,
                       pt, bidx, gxp, gyp, W1fT, W2fT, W3fT, W4T, Bf,
                       h, count, list);

    hipLaunchKernelGGL(pool_gather, dim3(GXD / 8, (GYD + 31) / 32, NBATCH),
                       dim3(512), 0, stream, count, list, h, (float*)d_out);
}